// Round 15
// baseline (504.754 us; speedup 1.0000x reference)
//
#include <hip/hip_runtime.h>

#define BN_EPS 1e-4f
#define BKT_SH 7          // 128 outputs per bucket
#define NBUCK_MAX 2560
#define CBLK 1024         // blocks in count/place phases (4 blocks/CU)
#define LDSCAP 4096       // max records per place-block (chunk = 3956)
#define P3CAP 2048        // max records per bucket

typedef __attribute__((ext_vector_type(8))) short short8;   // 8 bf16
typedef __attribute__((ext_vector_type(4))) float f32x4;    // MFMA acc
typedef __attribute__((ext_vector_type(4))) float floatv4;
typedef unsigned int uint;

union U4S8 { uint4 u; short8 s; };

// float -> bf16 bits, round-to-nearest-even
static __device__ __forceinline__ unsigned short f2bf(float f) {
    unsigned u = __float_as_uint(f);
    unsigned r = (u + 0x7FFFu + ((u >> 16) & 1u)) >> 16;
    return (unsigned short)r;
}

// ---------------- BN stats over f32 [N,32]: per-channel sum & sumsq -------
__global__ void stats_f32(const float* __restrict__ x,
                          float* __restrict__ stats, int total4) {
    const int t = threadIdx.x;
    long idx = (long)blockIdx.x * 256 + t;
    const long stride = (long)gridDim.x * 256;
    float s[4] = {0.f, 0.f, 0.f, 0.f}, q[4] = {0.f, 0.f, 0.f, 0.f};
    const floatv4* x4 = (const floatv4*)x;
    for (long e = idx; e < total4; e += stride) {
        floatv4 v = x4[e];
#pragma unroll
        for (int j = 0; j < 4; ++j) { s[j] += v[j]; q[j] += v[j] * v[j]; }
    }
    __shared__ float red[256][4];
#pragma unroll
    for (int j = 0; j < 4; ++j) red[t][j] = s[j];
    __syncthreads();
    if (t < 32) {
        float a = 0.f;
        const int grp = t >> 2, j = t & 3;
#pragma unroll
        for (int m = 0; m < 32; ++m) a += red[grp + 8 * m][j];
        atomicAdd(&stats[t], a);
    }
    __syncthreads();
#pragma unroll
    for (int j = 0; j < 4; ++j) red[t][j] = q[j];
    __syncthreads();
    if (t < 32) {
        float a = 0.f;
        const int grp = t >> 2, j = t & 3;
#pragma unroll
        for (int m = 0; m < 32; ++m) a += red[grp + 8 * m][j];
        atomicAdd(&stats[32 + t], a);
    }
}

// ---------------- BN stats over bf16 [N,32] ----------------
__global__ void stats_bf16(const ushort* __restrict__ x,
                           float* __restrict__ stats, int n8) {
    const int t = threadIdx.x;
    long idx = (long)blockIdx.x * 256 + t;
    const long stride = (long)gridDim.x * 256;
    float s[8] = {0}, q[8] = {0};
    const uint4* x8 = (const uint4*)x;
    for (long e = idx; e < n8; e += stride) {
        uint4 v = x8[e];
        uint w0 = v.x, w1 = v.y, w2 = v.z, w3 = v.w;
        float f0 = __uint_as_float(w0 << 16), f1 = __uint_as_float(w0 & 0xFFFF0000u);
        float f2 = __uint_as_float(w1 << 16), f3 = __uint_as_float(w1 & 0xFFFF0000u);
        float f4 = __uint_as_float(w2 << 16), f5 = __uint_as_float(w2 & 0xFFFF0000u);
        float f6 = __uint_as_float(w3 << 16), f7 = __uint_as_float(w3 & 0xFFFF0000u);
        s[0]+=f0; q[0]+=f0*f0; s[1]+=f1; q[1]+=f1*f1;
        s[2]+=f2; q[2]+=f2*f2; s[3]+=f3; q[3]+=f3*f3;
        s[4]+=f4; q[4]+=f4*f4; s[5]+=f5; q[5]+=f5*f5;
        s[6]+=f6; q[6]+=f6*f6; s[7]+=f7; q[7]+=f7*f7;
    }
    __shared__ float red[256][8];
#pragma unroll
    for (int j = 0; j < 8; ++j) red[t][j] = s[j];
    __syncthreads();
    if (t < 32) {
        float a = 0.f;
        const int grp = t >> 3, j = t & 7;
#pragma unroll
        for (int m = 0; m < 64; ++m) a += red[grp + 4 * m][j];
        atomicAdd(&stats[t], a);
    }
    __syncthreads();
#pragma unroll
    for (int j = 0; j < 8; ++j) red[t][j] = q[j];
    __syncthreads();
    if (t < 32) {
        float a = 0.f;
        const int grp = t >> 3, j = t & 7;
#pragma unroll
        for (int m = 0; m < 64; ++m) a += red[grp + 4 * m][j];
        atomicAdd(&stats[32 + t], a);
    }
}

// ---------------- bn_relu + cast to bf16 (f32 input) ----------------
__global__ void bnrelu_f32(const float* __restrict__ x,
                           const float* __restrict__ stats,
                           ushort* __restrict__ xb, int n8, int N) {
    int idx = blockIdx.x * 256 + threadIdx.x;
    if (idx >= n8) return;
    const int c0 = (idx & 3) * 8;
    const float invN = 1.0f / (float)N;
    floatv4 v0 = *(const floatv4*)(x + (size_t)idx * 8);
    floatv4 v1 = *(const floatv4*)(x + (size_t)idx * 8 + 4);
    uint r[8];
#pragma unroll
    for (int j = 0; j < 8; ++j) {
        const int c = c0 + j;
        float mu = stats[c] * invN;
        float var = stats[32 + c] * invN - mu * mu;
        float rs = rsqrtf(var + BN_EPS);
        float f = (j < 4) ? v0[j] : v1[j - 4];
        float xn = fmaxf((f - mu) * rs, 0.f);
        r[j] = (uint)f2bf(xn);
    }
    uint4 o;
    o.x = r[0] | (r[1] << 16); o.y = r[2] | (r[3] << 16);
    o.z = r[4] | (r[5] << 16); o.w = r[6] | (r[7] << 16);
    *(uint4*)(xb + (size_t)idx * 8) = o;
}

// ---------------- bn_relu + cast to bf16 (bf16 input) ----------------
__global__ void bnrelu_bf16(const ushort* __restrict__ h,
                            const float* __restrict__ stats,
                            ushort* __restrict__ xb, int n8, int N) {
    int idx = blockIdx.x * 256 + threadIdx.x;
    if (idx >= n8) return;
    const int c0 = (idx & 3) * 8;
    const float invN = 1.0f / (float)N;
    uint4 v = *(const uint4*)(h + (size_t)idx * 8);
    uint w[4] = {v.x, v.y, v.z, v.w};
    uint r[8];
#pragma unroll
    for (int j = 0; j < 8; ++j) {
        const int c = c0 + j;
        float mu = stats[c] * invN;
        float var = stats[32 + c] * invN - mu * mu;
        float rs = rsqrtf(var + BN_EPS);
        uint bits = (j & 1) ? (w[j >> 1] & 0xFFFF0000u) : (w[j >> 1] << 16);
        float f = __uint_as_float(bits);
        float xn = fmaxf((f - mu) * rs, 0.f);
        r[j] = (uint)f2bf(xn);
    }
    uint4 o;
    o.x = r[0] | (r[1] << 16); o.y = r[2] | (r[3] << 16);
    o.z = r[4] | (r[5] << 16); o.w = r[6] | (r[7] << 16);
    *(uint4*)(xb + (size_t)idx * 8) = o;
}

// --- prep: W->bf16^T, zero row N of xb, pack xyzb[N]={x,y,z,batch} --------
__global__ void prep(const float* __restrict__ W1, const float* __restrict__ W2,
                     ushort* __restrict__ Wt1, ushort* __restrict__ Wt2,
                     ushort* __restrict__ xb,
                     const float* __restrict__ xyz, const int* __restrict__ batch,
                     floatv4* __restrict__ xyzb, int N) {
    int idx = blockIdx.x * 256 + threadIdx.x;
    if (idx < 27 * 1024) {
        int k = idx >> 10, r = idx & 1023, co = r >> 5, ci = r & 31;
        Wt1[(k << 10) + (co << 5) + ci] = f2bf(W1[(k << 10) + (ci << 5) + co]);
    } else if (idx < 2 * 27 * 1024) {
        int i2 = idx - 27 * 1024;
        int k = i2 >> 10, r = i2 & 1023, co = r >> 5, ci = r & 31;
        Wt2[(k << 10) + (co << 5) + ci] = f2bf(W2[(k << 10) + (ci << 5) + co]);
    } else if (idx < 2 * 27 * 1024 + 32) {
        xb[(size_t)N * 32 + (idx - 2 * 27 * 1024)] = 0;
    } else {
        int i = idx - (2 * 27 * 1024 + 32);
        if (i < N) {
            floatv4 v;
            v[0] = xyz[(size_t)i * 3 + 0];
            v[1] = xyz[(size_t)i * 3 + 1];
            v[2] = xyz[(size_t)i * 3 + 2];
            v[3] = (float)batch[i];
            xyzb[i] = v;
        }
    }
}

// ============ CSR build: atomic-free MSD bucket sort (shape-generic) ======
// bucket = pout >> 7. Record payload = (k<<19)|pin (24b). Used for BOTH the
// conv pairs (KP=27*P) and the downsample pairs (KP=P2, K=1 -> k=0).

__global__ void p1_count(const int* __restrict__ pin, const int* __restrict__ pout,
                         uint* __restrict__ cntmat, int KP, int chunk, int nbuck) {
    __shared__ uint H[NBUCK_MAX];
    const int t = threadIdx.x;
    for (int i = t; i < nbuck; i += 256) H[i] = 0;
    __syncthreads();
    const int r0 = blockIdx.x * chunk;
    const int r1 = min(KP, r0 + chunk);
    for (int r = r0 + t; r < r1; r += 256)
        if (pin[r] >= 0) atomicAdd(&H[((uint)pout[r]) >> BKT_SH], 1u);
    __syncthreads();
    uint* row = cntmat + (size_t)blockIdx.x * nbuck;
    for (int i = t; i < nbuck; i += 256) row[i] = H[i];
}

// p2: per-bucket exclusive scan over CBLK rows. Block = 16 buckets x 16
// segments of (CBLK/16) rows. 16 consecutive buckets = 64B per 16 lanes.
__global__ void p2_colscan(uint* __restrict__ cntmat, uint* __restrict__ btot,
                           int nbuck) {
    const int tid = threadIdx.x;
    const int bi  = tid & 15;
    const int seg = tid >> 4;            // 0..15
    const int b   = blockIdx.x * 16 + bi;
    const int rpseg = CBLK / 16;         // 64 rows per segment
    const bool valid = (b < nbuck);
    uint s = 0;
    if (valid) {
        for (int u = 0; u < rpseg; ++u)
            s += cntmat[(size_t)(seg * rpseg + u) * nbuck + b];
    }
    __shared__ uint ss[16][16];
    ss[seg][bi] = s;
    __syncthreads();
    uint pre = 0;
    for (int g = 0; g < seg; ++g) pre += ss[g][bi];
    if (valid && seg == 15) btot[b] = pre + s;
    if (valid) {
        uint run = pre;
        for (int u = 0; u < rpseg; ++u) {
            size_t idx = (size_t)(seg * rpseg + u) * nbuck + b;
            uint v = cntmat[idx];
            cntmat[idx] = run;           // exclusive over blocks
            run += v;
        }
    }
}

// p3: both bucket-scans (conv and ds) in one launch; blockIdx selects set.
__global__ void p3_bucketscan2(const uint* __restrict__ btotA, uint* __restrict__ bbaseA,
                               uint* __restrict__ startsA, int nbuckA, int NA,
                               const uint* __restrict__ btotB, uint* __restrict__ bbaseB,
                               uint* __restrict__ startsB, int nbuckB, int NB) {
    const uint* btot; uint* bbase; uint* starts; int nbuck; int N;
    if (blockIdx.x == 0) { btot = btotA; bbase = bbaseA; starts = startsA; nbuck = nbuckA; N = NA; }
    else                 { btot = btotB; bbase = bbaseB; starts = startsB; nbuck = nbuckB; N = NB; }
    const int t = threadIdx.x;
    __shared__ uint part[256];
    uint loc[10]; uint s = 0;
#pragma unroll
    for (int u = 0; u < 10; ++u) {
        int i = t * 10 + u;
        loc[u] = (i < nbuck) ? btot[i] : 0;
        s += loc[u];
    }
    part[t] = s;
    __syncthreads();
    for (int off = 1; off < 256; off <<= 1) {
        uint y = (t >= off) ? part[t - off] : 0;
        __syncthreads();
        part[t] += y;
        __syncthreads();
    }
    uint run = part[t] - s;
#pragma unroll
    for (int u = 0; u < 10; ++u) {
        int i = t * 10 + u;
        if (i < nbuck) { bbase[i] = run; run += loc[u]; }
    }
    if (t == 255) { bbase[nbuck] = run; starts[N] = run; }
}

// phase 4: counting-sort block's records by bucket in LDS, write bucket runs.
// bucket id stored in u16 sidecar at placement -> no binary search at write.
__global__ __launch_bounds__(256)
void p4_place(const int* __restrict__ pin, const int* __restrict__ pout,
              const uint* __restrict__ cntmat, const uint* __restrict__ bbase,
              uint* __restrict__ tmp, int KP, int P, int chunk, int nbuck) {
    __shared__ uint recs[LDSCAP];
    __shared__ ushort bof[LDSCAP];
    __shared__ uint H[NBUCK_MAX + 1];
    __shared__ uint C[NBUCK_MAX];
    __shared__ uint part[256];
    const int t = threadIdx.x;
    const int j = blockIdx.x;
    for (int i = t; i < nbuck; i += 256) H[i] = 0;
    __syncthreads();
    const int r0 = j * chunk;
    const int r1 = min(KP, r0 + chunk);
    for (int r = r0 + t; r < r1; r += 256)
        if (pin[r] >= 0) atomicAdd(&H[((uint)pout[r]) >> BKT_SH], 1u);
    __syncthreads();
    uint loc[10]; uint s = 0;
#pragma unroll
    for (int u = 0; u < 10; ++u) {
        int i = t * 10 + u;
        loc[u] = (i < nbuck) ? H[i] : 0;
        s += loc[u];
    }
    __syncthreads();
    part[t] = s;
    __syncthreads();
    for (int off = 1; off < 256; off <<= 1) {
        uint y = (t >= off) ? part[t - off] : 0;
        __syncthreads();
        part[t] += y;
        __syncthreads();
    }
    uint run = part[t] - s;
#pragma unroll
    for (int u = 0; u < 10; ++u) {
        int i = t * 10 + u;
        if (i < nbuck) { uint c = loc[u]; H[i] = run; run += c; }
    }
    if (t == 255) H[nbuck] = run;
    __syncthreads();
    for (int i = t; i < nbuck; i += 256) C[i] = H[i];   // cursors
    __syncthreads();
    for (int r = r0 + t; r < r1; r += 256) {
        int ii = pin[r];
        if (ii < 0) continue;
        uint po = (uint)pout[r];
        uint b = po >> BKT_SH;
        uint k = (uint)r / (uint)P;
        uint pos = atomicAdd(&C[b], 1u);
        recs[pos] = ((po & 127u) << 24) | (k << 19) | (uint)ii;
        bof[pos] = (ushort)b;
    }
    __syncthreads();
    const uint tot = H[nbuck];
    for (int i = t; i < nbuck; i += 256)
        C[i] = bbase[i] + cntmat[(size_t)j * nbuck + i] - H[i];  // dest bias
    __syncthreads();
    for (uint sdx = t; sdx < tot; sdx += 256) {
        uint b = (uint)bof[sdx];
        tmp[C[b] + sdx] = recs[sdx];
    }
}

// phase 5: per-bucket counting-sort by output -> starts + entries.
// entries MAY ALIAS tmp (whole range staged into LDS before any write).
__global__ void p5_fine(const uint* tmp, const uint* __restrict__ bbase,
                        uint* entries, uint* __restrict__ starts, int N) {
    __shared__ uint recs[P3CAP];
    __shared__ uint cnt[128];
    __shared__ uint curl[128];
    const int b = blockIdx.x;
    const int t = threadIdx.x;
    const uint e0 = bbase[b];
    uint nrec = bbase[b + 1] - e0;
    if (nrec > P3CAP) nrec = P3CAP;
    for (uint s = t; s < nrec; s += 256) recs[s] = tmp[e0 + s];
    if (t < 128) { cnt[t] = 0; curl[t] = 0; }
    __syncthreads();
    for (uint s = t; s < nrec; s += 256) atomicAdd(&cnt[recs[s] >> 24], 1u);
    __syncthreads();
    uint orig = (t < 128) ? cnt[t] : 0;
    for (int off = 1; off < 128; off <<= 1) {
        uint y = (t < 128 && t >= off) ? cnt[t - off] : 0;
        __syncthreads();
        if (t < 128) cnt[t] += y;
        __syncthreads();
    }
    if (t < 128) cnt[t] -= orig;
    __syncthreads();
    const int o0 = b << BKT_SH;
    if (t < 128 && o0 + t < N) starts[o0 + t] = e0 + cnt[t];
    for (uint s = t; s < nrec; s += 256) {
        uint lo = recs[s] >> 24;
        uint idx = atomicAdd(&curl[lo], 1u);
        entries[e0 + cnt[lo] + idx] = recs[s] & 0x00FFFFFFu;
    }
}

// ------- CSR-gather MFMA conv: wave-independent (round-13 body) -----------
template <bool FINAL>
__global__ void conv_csr(const ushort* __restrict__ xb,   // [N+1][32], row N = 0
                         const ushort* __restrict__ Wt,   // [27][32 cout][32 cin]
                         const uint* __restrict__ starts,
                         const uint* __restrict__ entries,
                         const float* __restrict__ iden,
                         float* __restrict__ outf,
                         ushort* __restrict__ outb,
                         int N) {
    const int w  = threadIdx.x >> 6;
    const int l  = threadIdx.x & 63;
    const int m  = l & 15;     // output-within-tile / C col (cout)
    const int iq = l >> 4;     // cin chunk iq*8..+7 ; C rows iq*4..+3
    const int o0 = (blockIdx.x * 4 + w) * 16;

    __shared__ uint eld[4][384];

    if (o0 >= N) return;       // wave-uniform exit; no barriers in this kernel

    const uint s0 = starts[o0];
    const uint sm = starts[o0 + m];
    const uint se = starts[o0 + m + 1];
    uint total = starts[o0 + 16] - s0;
    if (total > 384) total = 384;
    for (uint t = l; t < total; t += 64)
        eld[w][t] = entries[s0 + t];
    asm volatile("s_waitcnt lgkmcnt(0) vmcnt(0)" ::: "memory");
    __builtin_amdgcn_sched_barrier(0);

    if (iq == 0) {
        const uint a = sm - s0, bnd = se - s0;
        for (uint i = a + 1; i < bnd; ++i) {
            uint key = eld[w][i];
            uint j = i;
            while (j > a && eld[w][j - 1] > key) { eld[w][j] = eld[w][j - 1]; --j; }
            eld[w][j] = key;
        }
    }
    asm volatile("s_waitcnt lgkmcnt(0)" ::: "memory");
    __builtin_amdgcn_sched_barrier(0);

    f32x4 c0 = {0.f, 0.f, 0.f, 0.f};
    f32x4 c1 = {0.f, 0.f, 0.f, 0.f};

    uint q = sm - s0;
    const uint e = se - s0;
    uint ent = (q < e) ? eld[w][q] : 0xFFFFFFFFu;

    for (int k = 0; k < 27; ++k) {
        const ushort* wk = Wt + (k << 10);
        U4S8 b0, b1;
        b0.u = *(const uint4*)(wk + m * 32 + iq * 8);
        b1.u = *(const uint4*)(wk + (m + 16) * 32 + iq * 8);

        float a0=0.f,a1=0.f,a2=0.f,a3=0.f,a4=0.f,a5=0.f,a6=0.f,a7=0.f;
        bool got = false;
        while ((ent >> 19) == (uint)k) {
            got = true;
            const uint pi = ent & 0x7FFFFu;
            uint4 v = *(const uint4*)(xb + (size_t)pi * 32 + iq * 8);
            a0 += __uint_as_float(v.x << 16);
            a1 += __uint_as_float(v.x & 0xFFFF0000u);
            a2 += __uint_as_float(v.y << 16);
            a3 += __uint_as_float(v.y & 0xFFFF0000u);
            a4 += __uint_as_float(v.z << 16);
            a5 += __uint_as_float(v.z & 0xFFFF0000u);
            a6 += __uint_as_float(v.w << 16);
            a7 += __uint_as_float(v.w & 0xFFFF0000u);
            ++q;
            ent = (q < e) ? eld[w][q] : 0xFFFFFFFFu;
        }
        if (__any(got)) {
            U4S8 af;
            asm volatile("v_cvt_pk_bf16_f32 %0, %1, %2" : "=v"(af.u.x) : "v"(a0), "v"(a1));
            asm volatile("v_cvt_pk_bf16_f32 %0, %1, %2" : "=v"(af.u.y) : "v"(a2), "v"(a3));
            asm volatile("v_cvt_pk_bf16_f32 %0, %1, %2" : "=v"(af.u.z) : "v"(a4), "v"(a5));
            asm volatile("v_cvt_pk_bf16_f32 %0, %1, %2" : "=v"(af.u.w) : "v"(a6), "v"(a7));
            c0 = __builtin_amdgcn_mfma_f32_16x16x32_bf16(af.s, b0.s, c0, 0, 0, 0);
            c1 = __builtin_amdgcn_mfma_f32_16x16x32_bf16(af.s, b1.s, c1, 0, 0, 0);
        }
    }

#pragma unroll
    for (int j = 0; j < 4; ++j) {
        const long ro = (long)(o0 + iq * 4 + j) * 32;
        if (FINAL) {
            outf[ro + m]      = c0[j] + iden[ro + m];
            outf[ro + 16 + m] = c1[j] + iden[ro + 16 + m];
        } else {
            outb[ro + m]      = f2bf(c0[j]);
            outb[ro + 16 + m] = f2bf(c1[j]);
        }
    }
}

// ---------------- downsample: CSR gather over packed xyzb (1 line/entry) --
__global__ void ds_gather(const floatv4* __restrict__ xyzb,
                          const uint* __restrict__ starts2,
                          const uint* __restrict__ entries2,
                          float* __restrict__ out_xyz,
                          float* __restrict__ out_batch, int M) {
    int o = blockIdx.x * 256 + threadIdx.x;
    if (o >= M) return;
    const uint s = starts2[o], e = starts2[o + 1];
    float sx = 0.f, sy = 0.f, sz = 0.f, sb = 0.f;
    for (uint q = s; q < e; ++q) {
        uint i = entries2[q] & 0x00FFFFFFu;
        floatv4 v = xyzb[i];
        sx += v[0]; sy += v[1]; sz += v[2]; sb += v[3];
    }
    float c = fmaxf((float)(e - s), 1.0f);
    float inv = 1.0f / c;
    out_xyz[(long)o * 3 + 0] = sx * inv;
    out_xyz[(long)o * 3 + 1] = sy * inv;
    out_xyz[(long)o * 3 + 2] = sz * inv;
    out_batch[o] = sb * inv;
}

extern "C" void kernel_launch(void* const* d_in, const int* in_sizes, int n_in,
                              void* d_out, int out_size, void* d_ws, size_t ws_size,
                              hipStream_t stream) {
    const float* feats = (const float*)d_in[0];
    const float* xyz   = (const float*)d_in[1];
    const int*   batch = (const int*)d_in[2];
    const int*   pin   = (const int*)d_in[3];
    const int*   pout  = (const int*)d_in[4];
    const int*   dsin  = (const int*)d_in[5];
    const int*   dsout = (const int*)d_in[6];
    const float* W1    = (const float*)d_in[7];
    const float* W2    = (const float*)d_in[8];

    const int N   = in_sizes[0] / 32;
    const int K   = 27;
    const int P   = in_sizes[3] / K;
    const int KP  = K * P;
    const int P2n = in_sizes[5];
    const int M   = (out_size - N * 32) / 4;
    const int nbuck = (N + 127) >> BKT_SH;       // 2344 for N=300000
    const int chunk = (KP + CBLK - 1) / CBLK;    // 3956 <= LDSCAP
    const int nbuck2 = (M + 127) >> BKT_SH;      // 293
    const int chunk2 = (P2n + CBLK - 1) / CBLK;  // 293

    auto align256 = [](size_t x) { return (x + 255) & ~(size_t)255; };
    char* base = (char*)d_ws;
    size_t off = 0;
    float* stats1 = (float*)(base + off); off += 256;
    float* stats2 = (float*)(base + off); off += 256;
    const size_t zero_end = off;
    uint* cntmat  = (uint*)(base + off);  off = align256(off + (size_t)CBLK * nbuck * 4);
    uint* btot    = (uint*)(base + off);  off = align256(off + (size_t)nbuck * 4);
    uint* bbase   = (uint*)(base + off);  off = align256(off + (size_t)(nbuck + 1) * 4);
    uint* starts  = (uint*)(base + off);  off = align256(off + (size_t)(N + 1) * 4);
    uint* tmp     = (uint*)(base + off);  off = align256(off + (size_t)KP * 4);
    uint* entries = tmp;                  // built in place by p5
    uint* cntmat2 = (uint*)(base + off);  off = align256(off + (size_t)CBLK * nbuck2 * 4);
    uint* btot2   = (uint*)(base + off);  off = align256(off + (size_t)nbuck2 * 4);
    uint* bbase2  = (uint*)(base + off);  off = align256(off + (size_t)(nbuck2 + 1) * 4);
    uint* starts2 = (uint*)(base + off);  off = align256(off + (size_t)(M + 1) * 4);
    uint* tmp2    = (uint*)(base + off);  off = align256(off + (size_t)P2n * 4);
    uint* entries2 = tmp2;                // built in place by p5
    ushort* Wt1   = (ushort*)(base + off); off = align256(off + 27 * 1024 * 2);
    ushort* Wt2   = (ushort*)(base + off); off = align256(off + 27 * 1024 * 2);
    ushort* xb    = (ushort*)(base + off); off = align256(off + (size_t)(N + 1) * 64);
    ushort* hacc  = (ushort*)(base + off); off = align256(off + (size_t)N * 64);
    floatv4* xyzb = (floatv4*)(base + off); off = align256(off + (size_t)N * 16);

    hipMemsetAsync(d_ws, 0, zero_end, stream);

    // W -> bf16 transposed + zero row N of xb + pack xyzb (merged)
    prep<<<(2 * 27 * 1024 + 32 + N + 255) / 256, 256, 0, stream>>>(
        W1, W2, Wt1, Wt2, xb, xyz, batch, xyzb, N);

    // CSR build for conv pairs (shared by both convs)
    p1_count<<<CBLK, 256, 0, stream>>>(pin, pout, cntmat, KP, chunk, nbuck);
    p2_colscan<<<(nbuck + 15) / 16, 256, 0, stream>>>(cntmat, btot, nbuck);
    // CSR build for downsample pairs (K=1 -> k=0)
    p1_count<<<CBLK, 256, 0, stream>>>(dsin, dsout, cntmat2, P2n, chunk2, nbuck2);
    p2_colscan<<<(nbuck2 + 15) / 16, 256, 0, stream>>>(cntmat2, btot2, nbuck2);
    // both bucket scans in one launch
    p3_bucketscan2<<<2, 256, 0, stream>>>(btot, bbase, starts, nbuck, N,
                                          btot2, bbase2, starts2, nbuck2, M);
    p4_place<<<CBLK, 256, 0, stream>>>(pin, pout, cntmat, bbase, tmp, KP, P, chunk, nbuck);
    p5_fine<<<nbuck, 256, 0, stream>>>(tmp, bbase, entries, starts, N);
    p4_place<<<CBLK, 256, 0, stream>>>(dsin, dsout, cntmat2, bbase2, tmp2, P2n, P2n, chunk2, nbuck2);
    p5_fine<<<nbuck2, 256, 0, stream>>>(tmp2, bbase2, entries2, starts2, M);

    // conv1: bn_relu(feats) -> W1 -> hacc (bf16)
    stats_f32<<<1024, 256, 0, stream>>>(feats, stats1, N * 8);
    bnrelu_f32<<<(N * 4 + 255) / 256, 256, 0, stream>>>(feats, stats1, xb, N * 4, N);
    const int cblocks = (N / 16 + 3) / 4;
    conv_csr<false><<<cblocks, 256, 0, stream>>>(xb, Wt1, starts, entries,
                                                 nullptr, nullptr, hacc, N);

    // conv2: bn_relu(hacc) -> W2 -> out (+ identity feats)
    stats_bf16<<<1024, 256, 0, stream>>>(hacc, stats2, N * 4);
    bnrelu_bf16<<<(N * 4 + 255) / 256, 256, 0, stream>>>(hacc, stats2, xb, N * 4, N);
    float* out = (float*)d_out;
    conv_csr<true><<<cblocks, 256, 0, stream>>>(xb, Wt2, starts, entries,
                                                feats, out, nullptr, N);

    // downsample: atomic-free CSR gather over packed xyzb
    ds_gather<<<(M + 255) / 256, 256, 0, stream>>>(xyzb, starts2, entries2,
                                                   out + (size_t)N * 32,
                                                   out + (size_t)N * 32 + (size_t)3 * M,
                                                   M);
}

// Round 16
// 465.347 us; speedup vs baseline: 1.0847x; 1.0847x over previous
//
#include <hip/hip_runtime.h>

#define BN_EPS 1e-4f
#define BKT_SH 8          // 256 outputs per bucket (local-out fits 8 bits)
#define NBUCK_MAX 2560
#define CBLK 1024         // blocks in count/place phases (4 blocks/CU)
#define LDSCAP 4096       // max records per place-block (chunk = 3956)
#define P3CAP 4096        // max records per bucket (avg ~3.1K)

typedef __attribute__((ext_vector_type(8))) short short8;   // 8 bf16
typedef __attribute__((ext_vector_type(4))) float f32x4;    // MFMA acc
typedef __attribute__((ext_vector_type(4))) float floatv4;
typedef unsigned int uint;

union U4S8 { uint4 u; short8 s; };

// float -> bf16 bits, round-to-nearest-even
static __device__ __forceinline__ unsigned short f2bf(float f) {
    unsigned u = __float_as_uint(f);
    unsigned r = (u + 0x7FFFu + ((u >> 16) & 1u)) >> 16;
    return (unsigned short)r;
}

// ---------------- BN stats over f32 [N,32]: per-channel sum & sumsq -------
__global__ void stats_f32(const float* __restrict__ x,
                          float* __restrict__ stats, int total4) {
    const int t = threadIdx.x;
    long idx = (long)blockIdx.x * 256 + t;
    const long stride = (long)gridDim.x * 256;
    float s[4] = {0.f, 0.f, 0.f, 0.f}, q[4] = {0.f, 0.f, 0.f, 0.f};
    const floatv4* x4 = (const floatv4*)x;
    for (long e = idx; e < total4; e += stride) {
        floatv4 v = x4[e];
#pragma unroll
        for (int j = 0; j < 4; ++j) { s[j] += v[j]; q[j] += v[j] * v[j]; }
    }
    __shared__ float red[256][4];
#pragma unroll
    for (int j = 0; j < 4; ++j) red[t][j] = s[j];
    __syncthreads();
    if (t < 32) {
        float a = 0.f;
        const int grp = t >> 2, j = t & 3;
#pragma unroll
        for (int m = 0; m < 32; ++m) a += red[grp + 8 * m][j];
        atomicAdd(&stats[t], a);
    }
    __syncthreads();
#pragma unroll
    for (int j = 0; j < 4; ++j) red[t][j] = q[j];
    __syncthreads();
    if (t < 32) {
        float a = 0.f;
        const int grp = t >> 2, j = t & 3;
#pragma unroll
        for (int m = 0; m < 32; ++m) a += red[grp + 8 * m][j];
        atomicAdd(&stats[32 + t], a);
    }
}

// ---------------- BN stats over bf16 [N,32] ----------------
__global__ void stats_bf16(const ushort* __restrict__ x,
                           float* __restrict__ stats, int n8) {
    const int t = threadIdx.x;
    long idx = (long)blockIdx.x * 256 + t;
    const long stride = (long)gridDim.x * 256;
    float s[8] = {0}, q[8] = {0};
    const uint4* x8 = (const uint4*)x;
    for (long e = idx; e < n8; e += stride) {
        uint4 v = x8[e];
        uint w0 = v.x, w1 = v.y, w2 = v.z, w3 = v.w;
        float f0 = __uint_as_float(w0 << 16), f1 = __uint_as_float(w0 & 0xFFFF0000u);
        float f2 = __uint_as_float(w1 << 16), f3 = __uint_as_float(w1 & 0xFFFF0000u);
        float f4 = __uint_as_float(w2 << 16), f5 = __uint_as_float(w2 & 0xFFFF0000u);
        float f6 = __uint_as_float(w3 << 16), f7 = __uint_as_float(w3 & 0xFFFF0000u);
        s[0]+=f0; q[0]+=f0*f0; s[1]+=f1; q[1]+=f1*f1;
        s[2]+=f2; q[2]+=f2*f2; s[3]+=f3; q[3]+=f3*f3;
        s[4]+=f4; q[4]+=f4*f4; s[5]+=f5; q[5]+=f5*f5;
        s[6]+=f6; q[6]+=f6*f6; s[7]+=f7; q[7]+=f7*f7;
    }
    __shared__ float red[256][8];
#pragma unroll
    for (int j = 0; j < 8; ++j) red[t][j] = s[j];
    __syncthreads();
    if (t < 32) {
        float a = 0.f;
        const int grp = t >> 3, j = t & 7;
#pragma unroll
        for (int m = 0; m < 64; ++m) a += red[grp + 4 * m][j];
        atomicAdd(&stats[t], a);
    }
    __syncthreads();
#pragma unroll
    for (int j = 0; j < 8; ++j) red[t][j] = q[j];
    __syncthreads();
    if (t < 32) {
        float a = 0.f;
        const int grp = t >> 3, j = t & 7;
#pragma unroll
        for (int m = 0; m < 64; ++m) a += red[grp + 4 * m][j];
        atomicAdd(&stats[32 + t], a);
    }
}

// ---------------- bn_relu + cast to bf16 (f32 input) ----------------
__global__ void bnrelu_f32(const float* __restrict__ x,
                           const float* __restrict__ stats,
                           ushort* __restrict__ xb, int n8, int N) {
    int idx = blockIdx.x * 256 + threadIdx.x;
    if (idx >= n8) return;
    const int c0 = (idx & 3) * 8;
    const float invN = 1.0f / (float)N;
    floatv4 v0 = *(const floatv4*)(x + (size_t)idx * 8);
    floatv4 v1 = *(const floatv4*)(x + (size_t)idx * 8 + 4);
    uint r[8];
#pragma unroll
    for (int j = 0; j < 8; ++j) {
        const int c = c0 + j;
        float mu = stats[c] * invN;
        float var = stats[32 + c] * invN - mu * mu;
        float rs = rsqrtf(var + BN_EPS);
        float f = (j < 4) ? v0[j] : v1[j - 4];
        float xn = fmaxf((f - mu) * rs, 0.f);
        r[j] = (uint)f2bf(xn);
    }
    uint4 o;
    o.x = r[0] | (r[1] << 16); o.y = r[2] | (r[3] << 16);
    o.z = r[4] | (r[5] << 16); o.w = r[6] | (r[7] << 16);
    *(uint4*)(xb + (size_t)idx * 8) = o;
}

// ---------------- bn_relu + cast to bf16 (bf16 input) ----------------
__global__ void bnrelu_bf16(const ushort* __restrict__ h,
                            const float* __restrict__ stats,
                            ushort* __restrict__ xb, int n8, int N) {
    int idx = blockIdx.x * 256 + threadIdx.x;
    if (idx >= n8) return;
    const int c0 = (idx & 3) * 8;
    const float invN = 1.0f / (float)N;
    uint4 v = *(const uint4*)(h + (size_t)idx * 8);
    uint w[4] = {v.x, v.y, v.z, v.w};
    uint r[8];
#pragma unroll
    for (int j = 0; j < 8; ++j) {
        const int c = c0 + j;
        float mu = stats[c] * invN;
        float var = stats[32 + c] * invN - mu * mu;
        float rs = rsqrtf(var + BN_EPS);
        uint bits = (j & 1) ? (w[j >> 1] & 0xFFFF0000u) : (w[j >> 1] << 16);
        float f = __uint_as_float(bits);
        float xn = fmaxf((f - mu) * rs, 0.f);
        r[j] = (uint)f2bf(xn);
    }
    uint4 o;
    o.x = r[0] | (r[1] << 16); o.y = r[2] | (r[3] << 16);
    o.z = r[4] | (r[5] << 16); o.w = r[6] | (r[7] << 16);
    *(uint4*)(xb + (size_t)idx * 8) = o;
}

// --- prep: W->bf16^T, zero row N of xb, pack xyzb[N]={x,y,z,batch} --------
__global__ void prep(const float* __restrict__ W1, const float* __restrict__ W2,
                     ushort* __restrict__ Wt1, ushort* __restrict__ Wt2,
                     ushort* __restrict__ xb,
                     const float* __restrict__ xyz, const int* __restrict__ batch,
                     floatv4* __restrict__ xyzb, int N) {
    int idx = blockIdx.x * 256 + threadIdx.x;
    if (idx < 27 * 1024) {
        int k = idx >> 10, r = idx & 1023, co = r >> 5, ci = r & 31;
        Wt1[(k << 10) + (co << 5) + ci] = f2bf(W1[(k << 10) + (ci << 5) + co]);
    } else if (idx < 2 * 27 * 1024) {
        int i2 = idx - 27 * 1024;
        int k = i2 >> 10, r = i2 & 1023, co = r >> 5, ci = r & 31;
        Wt2[(k << 10) + (co << 5) + ci] = f2bf(W2[(k << 10) + (ci << 5) + co]);
    } else if (idx < 2 * 27 * 1024 + 32) {
        xb[(size_t)N * 32 + (idx - 2 * 27 * 1024)] = 0;
    } else {
        int i = idx - (2 * 27 * 1024 + 32);
        if (i < N) {
            floatv4 v;
            v[0] = xyz[(size_t)i * 3 + 0];
            v[1] = xyz[(size_t)i * 3 + 1];
            v[2] = xyz[(size_t)i * 3 + 2];
            v[3] = (float)batch[i];
            xyzb[i] = v;
        }
    }
}

// ============ CSR build: atomic-free MSD bucket sort (shape-generic) ======
// bucket = pout >> 8 (256 outputs). Record = (po&255)<<24 | k<<19 | pin.

// p1 merged: blocks [0,CBLK) build set A (conv), [CBLK,2*CBLK) set B (ds).
__global__ void p1_count2(const int* __restrict__ pinA, const int* __restrict__ poutA,
                          uint* __restrict__ cntmatA, int KPA, int chunkA, int nbuckA,
                          const int* __restrict__ pinB, const int* __restrict__ poutB,
                          uint* __restrict__ cntmatB, int KPB, int chunkB, int nbuckB) {
    __shared__ uint H[NBUCK_MAX];
    const int t = threadIdx.x;
    const bool isA = (blockIdx.x < CBLK);
    const int j = isA ? blockIdx.x : (blockIdx.x - CBLK);
    const int* pin = isA ? pinA : pinB;
    const int* pout = isA ? poutA : poutB;
    uint* cntmat = isA ? cntmatA : cntmatB;
    const int KP = isA ? KPA : KPB;
    const int chunk = isA ? chunkA : chunkB;
    const int nbuck = isA ? nbuckA : nbuckB;
    for (int i = t; i < nbuck; i += 256) H[i] = 0;
    __syncthreads();
    const int r0 = j * chunk;
    const int r1 = min(KP, r0 + chunk);
    for (int r = r0 + t; r < r1; r += 256)
        if (pin[r] >= 0) atomicAdd(&H[((uint)pout[r]) >> BKT_SH], 1u);
    __syncthreads();
    uint* row = cntmat + (size_t)j * nbuck;
    for (int i = t; i < nbuck; i += 256) row[i] = H[i];
}

// p2 merged: blocks [0,nblkA) scan set A; rest set B.
__global__ void p2_colscan2(uint* __restrict__ cntmatA, uint* __restrict__ btotA,
                            int nbuckA, int nblkA,
                            uint* __restrict__ cntmatB, uint* __restrict__ btotB,
                            int nbuckB) {
    const bool isA = ((int)blockIdx.x < nblkA);
    const int blk = isA ? blockIdx.x : (blockIdx.x - nblkA);
    uint* cntmat = isA ? cntmatA : cntmatB;
    uint* btot = isA ? btotA : btotB;
    const int nbuck = isA ? nbuckA : nbuckB;
    const int tid = threadIdx.x;
    const int bi  = tid & 15;
    const int seg = tid >> 4;            // 0..15
    const int b   = blk * 16 + bi;
    const int rpseg = CBLK / 16;         // 64 rows per segment
    const bool valid = (b < nbuck);
    uint s = 0;
    if (valid) {
        for (int u = 0; u < rpseg; ++u)
            s += cntmat[(size_t)(seg * rpseg + u) * nbuck + b];
    }
    __shared__ uint ss[16][16];
    ss[seg][bi] = s;
    __syncthreads();
    uint pre = 0;
    for (int g = 0; g < seg; ++g) pre += ss[g][bi];
    if (valid && seg == 15) btot[b] = pre + s;
    if (valid) {
        uint run = pre;
        for (int u = 0; u < rpseg; ++u) {
            size_t idx = (size_t)(seg * rpseg + u) * nbuck + b;
            uint v = cntmat[idx];
            cntmat[idx] = run;           // exclusive over blocks
            run += v;
        }
    }
}

// p3: both bucket-scans in one launch; blockIdx selects set.
__global__ void p3_bucketscan2(const uint* __restrict__ btotA, uint* __restrict__ bbaseA,
                               uint* __restrict__ startsA, int nbuckA, int NA,
                               const uint* __restrict__ btotB, uint* __restrict__ bbaseB,
                               uint* __restrict__ startsB, int nbuckB, int NB) {
    const uint* btot; uint* bbase; uint* starts; int nbuck; int N;
    if (blockIdx.x == 0) { btot = btotA; bbase = bbaseA; starts = startsA; nbuck = nbuckA; N = NA; }
    else                 { btot = btotB; bbase = bbaseB; starts = startsB; nbuck = nbuckB; N = NB; }
    const int t = threadIdx.x;
    __shared__ uint part[256];
    uint loc[10]; uint s = 0;
#pragma unroll
    for (int u = 0; u < 10; ++u) {
        int i = t * 10 + u;
        loc[u] = (i < nbuck) ? btot[i] : 0;
        s += loc[u];
    }
    part[t] = s;
    __syncthreads();
    for (int off = 1; off < 256; off <<= 1) {
        uint y = (t >= off) ? part[t - off] : 0;
        __syncthreads();
        part[t] += y;
        __syncthreads();
    }
    uint run = part[t] - s;
#pragma unroll
    for (int u = 0; u < 10; ++u) {
        int i = t * 10 + u;
        if (i < nbuck) { bbase[i] = run; run += loc[u]; }
    }
    if (t == 255) { bbase[nbuck] = run; starts[N] = run; }
}

// phase 4: counting-sort block's records by bucket in LDS, write bucket runs.
__global__ __launch_bounds__(256)
void p4_place(const int* __restrict__ pin, const int* __restrict__ pout,
              const uint* __restrict__ cntmat, const uint* __restrict__ bbase,
              uint* __restrict__ tmp, int KP, int P, int chunk, int nbuck) {
    __shared__ uint recs[LDSCAP];
    __shared__ ushort bof[LDSCAP];
    __shared__ uint H[NBUCK_MAX + 1];
    __shared__ uint C[NBUCK_MAX];
    __shared__ uint part[256];
    const int t = threadIdx.x;
    const int j = blockIdx.x;
    for (int i = t; i < nbuck; i += 256) H[i] = 0;
    __syncthreads();
    const int r0 = j * chunk;
    const int r1 = min(KP, r0 + chunk);
    for (int r = r0 + t; r < r1; r += 256)
        if (pin[r] >= 0) atomicAdd(&H[((uint)pout[r]) >> BKT_SH], 1u);
    __syncthreads();
    uint loc[10]; uint s = 0;
#pragma unroll
    for (int u = 0; u < 10; ++u) {
        int i = t * 10 + u;
        loc[u] = (i < nbuck) ? H[i] : 0;
        s += loc[u];
    }
    __syncthreads();
    part[t] = s;
    __syncthreads();
    for (int off = 1; off < 256; off <<= 1) {
        uint y = (t >= off) ? part[t - off] : 0;
        __syncthreads();
        part[t] += y;
        __syncthreads();
    }
    uint run = part[t] - s;
#pragma unroll
    for (int u = 0; u < 10; ++u) {
        int i = t * 10 + u;
        if (i < nbuck) { uint c = loc[u]; H[i] = run; run += c; }
    }
    if (t == 255) H[nbuck] = run;
    __syncthreads();
    for (int i = t; i < nbuck; i += 256) C[i] = H[i];   // cursors
    __syncthreads();
    for (int r = r0 + t; r < r1; r += 256) {
        int ii = pin[r];
        if (ii < 0) continue;
        uint po = (uint)pout[r];
        uint b = po >> BKT_SH;
        uint k = (uint)r / (uint)P;
        uint pos = atomicAdd(&C[b], 1u);
        recs[pos] = ((po & 255u) << 24) | (k << 19) | (uint)ii;
        bof[pos] = (ushort)b;
    }
    __syncthreads();
    const uint tot = H[nbuck];
    for (int i = t; i < nbuck; i += 256)
        C[i] = bbase[i] + cntmat[(size_t)j * nbuck + i] - H[i];  // dest bias
    __syncthreads();
    for (uint sdx = t; sdx < tot; sdx += 256) {
        uint b = (uint)bof[sdx];
        tmp[C[b] + sdx] = recs[sdx];
    }
}

// phase 5: per-bucket counting-sort by local output (8-bit) -> starts+entries.
// entries MAY ALIAS tmp (whole range staged into LDS before any write).
__global__ void p5_fine(const uint* tmp, const uint* __restrict__ bbase,
                        uint* entries, uint* __restrict__ starts, int N) {
    __shared__ uint recs[P3CAP];
    __shared__ uint cnt[256];
    __shared__ uint curl[256];
    const int b = blockIdx.x;
    const int t = threadIdx.x;
    const uint e0 = bbase[b];
    uint nrec = bbase[b + 1] - e0;
    if (nrec > P3CAP) nrec = P3CAP;
    for (uint s = t; s < nrec; s += 256) recs[s] = tmp[e0 + s];
    cnt[t] = 0; curl[t] = 0;
    __syncthreads();
    for (uint s = t; s < nrec; s += 256) atomicAdd(&cnt[recs[s] >> 24], 1u);
    __syncthreads();
    uint orig = cnt[t];
    for (int off = 1; off < 256; off <<= 1) {
        uint y = (t >= off) ? cnt[t - off] : 0;
        __syncthreads();
        cnt[t] += y;
        __syncthreads();
    }
    cnt[t] -= orig;   // exclusive prefix per local output
    __syncthreads();
    const int o0 = b << BKT_SH;
    if (o0 + t < N) starts[o0 + t] = e0 + cnt[t];
    for (uint s = t; s < nrec; s += 256) {
        uint lo = recs[s] >> 24;
        uint idx = atomicAdd(&curl[lo], 1u);
        entries[e0 + cnt[lo] + idx] = recs[s] & 0x00FFFFFFu;
    }
}

// ------- CSR-gather MFMA conv: wave-independent (round-13 body) -----------
template <bool FINAL>
__global__ void conv_csr(const ushort* __restrict__ xb,   // [N+1][32], row N = 0
                         const ushort* __restrict__ Wt,   // [27][32 cout][32 cin]
                         const uint* __restrict__ starts,
                         const uint* __restrict__ entries,
                         const float* __restrict__ iden,
                         float* __restrict__ outf,
                         ushort* __restrict__ outb,
                         int N) {
    const int w  = threadIdx.x >> 6;
    const int l  = threadIdx.x & 63;
    const int m  = l & 15;     // output-within-tile / C col (cout)
    const int iq = l >> 4;     // cin chunk iq*8..+7 ; C rows iq*4..+3
    const int o0 = (blockIdx.x * 4 + w) * 16;

    __shared__ uint eld[4][384];

    if (o0 >= N) return;       // wave-uniform exit; no barriers in this kernel

    const uint s0 = starts[o0];
    const uint sm = starts[o0 + m];
    const uint se = starts[o0 + m + 1];
    uint total = starts[o0 + 16] - s0;
    if (total > 384) total = 384;
    for (uint t = l; t < total; t += 64)
        eld[w][t] = entries[s0 + t];
    asm volatile("s_waitcnt lgkmcnt(0) vmcnt(0)" ::: "memory");
    __builtin_amdgcn_sched_barrier(0);

    if (iq == 0) {
        const uint a = sm - s0, bnd = se - s0;
        for (uint i = a + 1; i < bnd; ++i) {
            uint key = eld[w][i];
            uint j = i;
            while (j > a && eld[w][j - 1] > key) { eld[w][j] = eld[w][j - 1]; --j; }
            eld[w][j] = key;
        }
    }
    asm volatile("s_waitcnt lgkmcnt(0)" ::: "memory");
    __builtin_amdgcn_sched_barrier(0);

    f32x4 c0 = {0.f, 0.f, 0.f, 0.f};
    f32x4 c1 = {0.f, 0.f, 0.f, 0.f};

    uint q = sm - s0;
    const uint e = se - s0;
    uint ent = (q < e) ? eld[w][q] : 0xFFFFFFFFu;

    for (int k = 0; k < 27; ++k) {
        const ushort* wk = Wt + (k << 10);
        U4S8 b0, b1;
        b0.u = *(const uint4*)(wk + m * 32 + iq * 8);
        b1.u = *(const uint4*)(wk + (m + 16) * 32 + iq * 8);

        float a0=0.f,a1=0.f,a2=0.f,a3=0.f,a4=0.f,a5=0.f,a6=0.f,a7=0.f;
        bool got = false;
        while ((ent >> 19) == (uint)k) {
            got = true;
            const uint pi = ent & 0x7FFFFu;
            uint4 v = *(const uint4*)(xb + (size_t)pi * 32 + iq * 8);
            a0 += __uint_as_float(v.x << 16);
            a1 += __uint_as_float(v.x & 0xFFFF0000u);
            a2 += __uint_as_float(v.y << 16);
            a3 += __uint_as_float(v.y & 0xFFFF0000u);
            a4 += __uint_as_float(v.z << 16);
            a5 += __uint_as_float(v.z & 0xFFFF0000u);
            a6 += __uint_as_float(v.w << 16);
            a7 += __uint_as_float(v.w & 0xFFFF0000u);
            ++q;
            ent = (q < e) ? eld[w][q] : 0xFFFFFFFFu;
        }
        if (__any(got)) {
            U4S8 af;
            asm volatile("v_cvt_pk_bf16_f32 %0, %1, %2" : "=v"(af.u.x) : "v"(a0), "v"(a1));
            asm volatile("v_cvt_pk_bf16_f32 %0, %1, %2" : "=v"(af.u.y) : "v"(a2), "v"(a3));
            asm volatile("v_cvt_pk_bf16_f32 %0, %1, %2" : "=v"(af.u.z) : "v"(a4), "v"(a5));
            asm volatile("v_cvt_pk_bf16_f32 %0, %1, %2" : "=v"(af.u.w) : "v"(a6), "v"(a7));
            c0 = __builtin_amdgcn_mfma_f32_16x16x32_bf16(af.s, b0.s, c0, 0, 0, 0);
            c1 = __builtin_amdgcn_mfma_f32_16x16x32_bf16(af.s, b1.s, c1, 0, 0, 0);
        }
    }

#pragma unroll
    for (int j = 0; j < 4; ++j) {
        const long ro = (long)(o0 + iq * 4 + j) * 32;
        if (FINAL) {
            outf[ro + m]      = c0[j] + iden[ro + m];
            outf[ro + 16 + m] = c1[j] + iden[ro + 16 + m];
        } else {
            outb[ro + m]      = f2bf(c0[j]);
            outb[ro + 16 + m] = f2bf(c1[j]);
        }
    }
}

// ---------------- downsample: CSR gather over packed xyzb -----------------
__global__ void ds_gather(const floatv4* __restrict__ xyzb,
                          const uint* __restrict__ starts2,
                          const uint* __restrict__ entries2,
                          float* __restrict__ out_xyz,
                          float* __restrict__ out_batch, int M) {
    int o = blockIdx.x * 256 + threadIdx.x;
    if (o >= M) return;
    const uint s = starts2[o], e = starts2[o + 1];
    float sx = 0.f, sy = 0.f, sz = 0.f, sb = 0.f;
    for (uint q = s; q < e; ++q) {
        uint i = entries2[q] & 0x00FFFFFFu;
        floatv4 v = xyzb[i];
        sx += v[0]; sy += v[1]; sz += v[2]; sb += v[3];
    }
    float c = fmaxf((float)(e - s), 1.0f);
    float inv = 1.0f / c;
    out_xyz[(long)o * 3 + 0] = sx * inv;
    out_xyz[(long)o * 3 + 1] = sy * inv;
    out_xyz[(long)o * 3 + 2] = sz * inv;
    out_batch[o] = sb * inv;
}

extern "C" void kernel_launch(void* const* d_in, const int* in_sizes, int n_in,
                              void* d_out, int out_size, void* d_ws, size_t ws_size,
                              hipStream_t stream) {
    const float* feats = (const float*)d_in[0];
    const float* xyz   = (const float*)d_in[1];
    const int*   batch = (const int*)d_in[2];
    const int*   pin   = (const int*)d_in[3];
    const int*   pout  = (const int*)d_in[4];
    const int*   dsin  = (const int*)d_in[5];
    const int*   dsout = (const int*)d_in[6];
    const float* W1    = (const float*)d_in[7];
    const float* W2    = (const float*)d_in[8];

    const int N   = in_sizes[0] / 32;
    const int K   = 27;
    const int P   = in_sizes[3] / K;
    const int KP  = K * P;
    const int P2n = in_sizes[5];
    const int M   = (out_size - N * 32) / 4;
    const int nbuck = (N + 255) >> BKT_SH;       // 1172 for N=300000
    const int chunk = (KP + CBLK - 1) / CBLK;    // 3956 <= LDSCAP
    const int nbuck2 = (M + 255) >> BKT_SH;      // 147
    const int chunk2 = (P2n + CBLK - 1) / CBLK;  // 293

    auto align256 = [](size_t x) { return (x + 255) & ~(size_t)255; };
    char* base = (char*)d_ws;
    size_t off = 0;
    float* stats1 = (float*)(base + off); off += 256;
    float* stats2 = (float*)(base + off); off += 256;
    const size_t zero_end = off;
    uint* cntmat  = (uint*)(base + off);  off = align256(off + (size_t)CBLK * nbuck * 4);
    uint* btot    = (uint*)(base + off);  off = align256(off + (size_t)nbuck * 4);
    uint* bbase   = (uint*)(base + off);  off = align256(off + (size_t)(nbuck + 1) * 4);
    uint* starts  = (uint*)(base + off);  off = align256(off + (size_t)(N + 1) * 4);
    uint* tmp     = (uint*)(base + off);  off = align256(off + (size_t)KP * 4);
    uint* entries = tmp;                  // built in place by p5
    uint* cntmat2 = (uint*)(base + off);  off = align256(off + (size_t)CBLK * nbuck2 * 4);
    uint* btot2   = (uint*)(base + off);  off = align256(off + (size_t)nbuck2 * 4);
    uint* bbase2  = (uint*)(base + off);  off = align256(off + (size_t)(nbuck2 + 1) * 4);
    uint* starts2 = (uint*)(base + off);  off = align256(off + (size_t)(M + 1) * 4);
    uint* tmp2    = (uint*)(base + off);  off = align256(off + (size_t)P2n * 4);
    uint* entries2 = tmp2;                // built in place by p5
    ushort* Wt1   = (ushort*)(base + off); off = align256(off + 27 * 1024 * 2);
    ushort* Wt2   = (ushort*)(base + off); off = align256(off + 27 * 1024 * 2);
    ushort* xb    = (ushort*)(base + off); off = align256(off + (size_t)(N + 1) * 64);
    ushort* hacc  = (ushort*)(base + off); off = align256(off + (size_t)N * 64);
    floatv4* xyzb = (floatv4*)(base + off); off = align256(off + (size_t)N * 16);

    hipMemsetAsync(d_ws, 0, zero_end, stream);

    // W -> bf16 transposed + zero row N of xb + pack xyzb (merged)
    prep<<<(2 * 27 * 1024 + 32 + N + 255) / 256, 256, 0, stream>>>(
        W1, W2, Wt1, Wt2, xb, xyz, batch, xyzb, N);

    // CSR builds (conv set A + ds set B), merged launches
    p1_count2<<<2 * CBLK, 256, 0, stream>>>(pin, pout, cntmat, KP, chunk, nbuck,
                                            dsin, dsout, cntmat2, P2n, chunk2, nbuck2);
    const int nblkA = (nbuck + 15) / 16, nblkB = (nbuck2 + 15) / 16;
    p2_colscan2<<<nblkA + nblkB, 256, 0, stream>>>(cntmat, btot, nbuck, nblkA,
                                                   cntmat2, btot2, nbuck2);
    p3_bucketscan2<<<2, 256, 0, stream>>>(btot, bbase, starts, nbuck, N,
                                          btot2, bbase2, starts2, nbuck2, M);
    p4_place<<<CBLK, 256, 0, stream>>>(pin, pout, cntmat, bbase, tmp, KP, P, chunk, nbuck);
    p5_fine<<<nbuck, 256, 0, stream>>>(tmp, bbase, entries, starts, N);
    p4_place<<<CBLK, 256, 0, stream>>>(dsin, dsout, cntmat2, bbase2, tmp2, P2n, P2n, chunk2, nbuck2);
    p5_fine<<<nbuck2, 256, 0, stream>>>(tmp2, bbase2, entries2, starts2, M);

    // conv1: bn_relu(feats) -> W1 -> hacc (bf16)
    stats_f32<<<1024, 256, 0, stream>>>(feats, stats1, N * 8);
    bnrelu_f32<<<(N * 4 + 255) / 256, 256, 0, stream>>>(feats, stats1, xb, N * 4, N);
    const int cblocks = (N / 16 + 3) / 4;
    conv_csr<false><<<cblocks, 256, 0, stream>>>(xb, Wt1, starts, entries,
                                                 nullptr, nullptr, hacc, N);

    // conv2: bn_relu(hacc) -> W2 -> out (+ identity feats)
    stats_bf16<<<1024, 256, 0, stream>>>(hacc, stats2, N * 4);
    bnrelu_bf16<<<(N * 4 + 255) / 256, 256, 0, stream>>>(hacc, stats2, xb, N * 4, N);
    float* out = (float*)d_out;
    conv_csr<true><<<cblocks, 256, 0, stream>>>(xb, Wt2, starts, entries,
                                                feats, out, nullptr, N);

    // downsample: atomic-free CSR gather over packed xyzb
    ds_gather<<<(M + 255) / 256, 256, 0, stream>>>(xyzb, starts2, entries2,
                                                   out + (size_t)N * 32,
                                                   out + (size_t)N * 32 + (size_t)3 * M,
                                                   M);
}

// Round 17
// 433.508 us; speedup vs baseline: 1.1643x; 1.0734x over previous
//
#include <hip/hip_runtime.h>

#define BN_EPS 1e-4f
#define BKT_SH 8          // 256 outputs per bucket (local-out fits 8 bits)
#define NBUCK_MAX 2560
#define CBLK 1024         // blocks in count/place phases (4 blocks/CU)
#define LDSCAP 4096       // max records per place-block (chunk = 3956)
#define P3CAP 4096        // max records per bucket (avg ~3.1K)

typedef __attribute__((ext_vector_type(8))) short short8;   // 8 bf16
typedef __attribute__((ext_vector_type(4))) float f32x4;    // MFMA acc
typedef __attribute__((ext_vector_type(4))) float floatv4;
typedef unsigned int uint;

union U4S8 { uint4 u; short8 s; };

// float -> bf16 bits, round-to-nearest-even
static __device__ __forceinline__ unsigned short f2bf(float f) {
    unsigned u = __float_as_uint(f);
    unsigned r = (u + 0x7FFFu + ((u >> 16) & 1u)) >> 16;
    return (unsigned short)r;
}

// ---------------- BN stats over bf16 [N,32] ----------------
__global__ void stats_bf16(const ushort* __restrict__ x,
                           float* __restrict__ stats, int n8) {
    const int t = threadIdx.x;
    long idx = (long)blockIdx.x * 256 + t;
    const long stride = (long)gridDim.x * 256;
    float s[8] = {0}, q[8] = {0};
    const uint4* x8 = (const uint4*)x;
    for (long e = idx; e < n8; e += stride) {
        uint4 v = x8[e];
        uint w0 = v.x, w1 = v.y, w2 = v.z, w3 = v.w;
        float f0 = __uint_as_float(w0 << 16), f1 = __uint_as_float(w0 & 0xFFFF0000u);
        float f2 = __uint_as_float(w1 << 16), f3 = __uint_as_float(w1 & 0xFFFF0000u);
        float f4 = __uint_as_float(w2 << 16), f5 = __uint_as_float(w2 & 0xFFFF0000u);
        float f6 = __uint_as_float(w3 << 16), f7 = __uint_as_float(w3 & 0xFFFF0000u);
        s[0]+=f0; q[0]+=f0*f0; s[1]+=f1; q[1]+=f1*f1;
        s[2]+=f2; q[2]+=f2*f2; s[3]+=f3; q[3]+=f3*f3;
        s[4]+=f4; q[4]+=f4*f4; s[5]+=f5; q[5]+=f5*f5;
        s[6]+=f6; q[6]+=f6*f6; s[7]+=f7; q[7]+=f7*f7;
    }
    __shared__ float red[256][8];
#pragma unroll
    for (int j = 0; j < 8; ++j) red[t][j] = s[j];
    __syncthreads();
    if (t < 32) {
        float a = 0.f;
        const int grp = t >> 3, j = t & 7;
#pragma unroll
        for (int m = 0; m < 64; ++m) a += red[grp + 4 * m][j];
        atomicAdd(&stats[t], a);
    }
    __syncthreads();
#pragma unroll
    for (int j = 0; j < 8; ++j) red[t][j] = q[j];
    __syncthreads();
    if (t < 32) {
        float a = 0.f;
        const int grp = t >> 3, j = t & 7;
#pragma unroll
        for (int m = 0; m < 64; ++m) a += red[grp + 4 * m][j];
        atomicAdd(&stats[32 + t], a);
    }
}

// ---------------- bn_relu + cast to bf16 (f32 input) ----------------
__global__ void bnrelu_f32(const float* __restrict__ x,
                           const float* __restrict__ stats,
                           ushort* __restrict__ xb, int n8, int N) {
    int idx = blockIdx.x * 256 + threadIdx.x;
    if (idx >= n8) return;
    const int c0 = (idx & 3) * 8;
    const float invN = 1.0f / (float)N;
    floatv4 v0 = *(const floatv4*)(x + (size_t)idx * 8);
    floatv4 v1 = *(const floatv4*)(x + (size_t)idx * 8 + 4);
    uint r[8];
#pragma unroll
    for (int j = 0; j < 8; ++j) {
        const int c = c0 + j;
        float mu = stats[c] * invN;
        float var = stats[32 + c] * invN - mu * mu;
        float rs = rsqrtf(var + BN_EPS);
        float f = (j < 4) ? v0[j] : v1[j - 4];
        float xn = fmaxf((f - mu) * rs, 0.f);
        r[j] = (uint)f2bf(xn);
    }
    uint4 o;
    o.x = r[0] | (r[1] << 16); o.y = r[2] | (r[3] << 16);
    o.z = r[4] | (r[5] << 16); o.w = r[6] | (r[7] << 16);
    *(uint4*)(xb + (size_t)idx * 8) = o;
}

// ---------------- bn_relu + cast to bf16 (bf16 input) ----------------
__global__ void bnrelu_bf16(const ushort* __restrict__ h,
                            const float* __restrict__ stats,
                            ushort* __restrict__ xb, int n8, int N) {
    int idx = blockIdx.x * 256 + threadIdx.x;
    if (idx >= n8) return;
    const int c0 = (idx & 3) * 8;
    const float invN = 1.0f / (float)N;
    uint4 v = *(const uint4*)(h + (size_t)idx * 8);
    uint w[4] = {v.x, v.y, v.z, v.w};
    uint r[8];
#pragma unroll
    for (int j = 0; j < 8; ++j) {
        const int c = c0 + j;
        float mu = stats[c] * invN;
        float var = stats[32 + c] * invN - mu * mu;
        float rs = rsqrtf(var + BN_EPS);
        uint bits = (j & 1) ? (w[j >> 1] & 0xFFFF0000u) : (w[j >> 1] << 16);
        float f = __uint_as_float(bits);
        float xn = fmaxf((f - mu) * rs, 0.f);
        r[j] = (uint)f2bf(xn);
    }
    uint4 o;
    o.x = r[0] | (r[1] << 16); o.y = r[2] | (r[3] << 16);
    o.z = r[4] | (r[5] << 16); o.w = r[6] | (r[7] << 16);
    *(uint4*)(xb + (size_t)idx * 8) = o;
}

// --- prep2: prep work (blocks < B0) + stats_f32 over feats (1024 blocks) --
__global__ void prep2(const float* __restrict__ W1, const float* __restrict__ W2,
                      ushort* __restrict__ Wt1, ushort* __restrict__ Wt2,
                      ushort* __restrict__ xb,
                      const float* __restrict__ xyz, const int* __restrict__ batch,
                      floatv4* __restrict__ xyzb, int N, int B0,
                      const float* __restrict__ feats, float* __restrict__ stats1,
                      int total4) {
    const int t = threadIdx.x;
    if ((int)blockIdx.x >= B0) {
        // ---- stats_f32 body over feats (grid-stride across 1024 blocks) ----
        const int bid = blockIdx.x - B0;
        long idx = (long)bid * 256 + t;
        const long stride = 1024L * 256;
        float s[4] = {0.f, 0.f, 0.f, 0.f}, q[4] = {0.f, 0.f, 0.f, 0.f};
        const floatv4* x4 = (const floatv4*)feats;
        for (long e = idx; e < total4; e += stride) {
            floatv4 v = x4[e];
#pragma unroll
            for (int j = 0; j < 4; ++j) { s[j] += v[j]; q[j] += v[j] * v[j]; }
        }
        __shared__ float red[256][4];
#pragma unroll
        for (int j = 0; j < 4; ++j) red[t][j] = s[j];
        __syncthreads();
        if (t < 32) {
            float a = 0.f;
            const int grp = t >> 2, j = t & 3;
#pragma unroll
            for (int m = 0; m < 32; ++m) a += red[grp + 8 * m][j];
            atomicAdd(&stats1[t], a);
        }
        __syncthreads();
#pragma unroll
        for (int j = 0; j < 4; ++j) red[t][j] = q[j];
        __syncthreads();
        if (t < 32) {
            float a = 0.f;
            const int grp = t >> 2, j = t & 3;
#pragma unroll
            for (int m = 0; m < 32; ++m) a += red[grp + 8 * m][j];
            atomicAdd(&stats1[32 + t], a);
        }
        return;
    }
    int idx = blockIdx.x * 256 + t;
    if (idx < 27 * 1024) {
        int k = idx >> 10, r = idx & 1023, co = r >> 5, ci = r & 31;
        Wt1[(k << 10) + (co << 5) + ci] = f2bf(W1[(k << 10) + (ci << 5) + co]);
    } else if (idx < 2 * 27 * 1024) {
        int i2 = idx - 27 * 1024;
        int k = i2 >> 10, r = i2 & 1023, co = r >> 5, ci = r & 31;
        Wt2[(k << 10) + (co << 5) + ci] = f2bf(W2[(k << 10) + (ci << 5) + co]);
    } else if (idx < 2 * 27 * 1024 + 32) {
        xb[(size_t)N * 32 + (idx - 2 * 27 * 1024)] = 0;
    } else {
        int i = idx - (2 * 27 * 1024 + 32);
        if (i < N) {
            floatv4 v;
            v[0] = xyz[(size_t)i * 3 + 0];
            v[1] = xyz[(size_t)i * 3 + 1];
            v[2] = xyz[(size_t)i * 3 + 2];
            v[3] = (float)batch[i];
            xyzb[i] = v;
        }
    }
}

// ============ CSR build: atomic-free MSD bucket sort (shape-generic) ======
// bucket = pout >> 8 (256 outputs). Record = (po&255)<<24 | k<<19 | pin.

// p1 merged: blocks [0,CBLK) build set A (conv), [CBLK,2*CBLK) set B (ds).
__global__ void p1_count2(const int* __restrict__ pinA, const int* __restrict__ poutA,
                          uint* __restrict__ cntmatA, int KPA, int chunkA, int nbuckA,
                          const int* __restrict__ pinB, const int* __restrict__ poutB,
                          uint* __restrict__ cntmatB, int KPB, int chunkB, int nbuckB) {
    __shared__ uint H[NBUCK_MAX];
    const int t = threadIdx.x;
    const bool isA = (blockIdx.x < CBLK);
    const int j = isA ? blockIdx.x : (blockIdx.x - CBLK);
    const int* pin = isA ? pinA : pinB;
    const int* pout = isA ? poutA : poutB;
    uint* cntmat = isA ? cntmatA : cntmatB;
    const int KP = isA ? KPA : KPB;
    const int chunk = isA ? chunkA : chunkB;
    const int nbuck = isA ? nbuckA : nbuckB;
    for (int i = t; i < nbuck; i += 256) H[i] = 0;
    __syncthreads();
    const int r0 = j * chunk;
    const int r1 = min(KP, r0 + chunk);
    for (int r = r0 + t; r < r1; r += 256)
        if (pin[r] >= 0) atomicAdd(&H[((uint)pout[r]) >> BKT_SH], 1u);
    __syncthreads();
    uint* row = cntmat + (size_t)j * nbuck;
    for (int i = t; i < nbuck; i += 256) row[i] = H[i];
}

// p2 merged: blocks [0,nblkA) scan set A; rest set B.
__global__ void p2_colscan2(uint* __restrict__ cntmatA, uint* __restrict__ btotA,
                            int nbuckA, int nblkA,
                            uint* __restrict__ cntmatB, uint* __restrict__ btotB,
                            int nbuckB) {
    const bool isA = ((int)blockIdx.x < nblkA);
    const int blk = isA ? blockIdx.x : (blockIdx.x - nblkA);
    uint* cntmat = isA ? cntmatA : cntmatB;
    uint* btot = isA ? btotA : btotB;
    const int nbuck = isA ? nbuckA : nbuckB;
    const int tid = threadIdx.x;
    const int bi  = tid & 15;
    const int seg = tid >> 4;            // 0..15
    const int b   = blk * 16 + bi;
    const int rpseg = CBLK / 16;         // 64 rows per segment
    const bool valid = (b < nbuck);
    uint s = 0;
    if (valid) {
        for (int u = 0; u < rpseg; ++u)
            s += cntmat[(size_t)(seg * rpseg + u) * nbuck + b];
    }
    __shared__ uint ss[16][16];
    ss[seg][bi] = s;
    __syncthreads();
    uint pre = 0;
    for (int g = 0; g < seg; ++g) pre += ss[g][bi];
    if (valid && seg == 15) btot[b] = pre + s;
    if (valid) {
        uint run = pre;
        for (int u = 0; u < rpseg; ++u) {
            size_t idx = (size_t)(seg * rpseg + u) * nbuck + b;
            uint v = cntmat[idx];
            cntmat[idx] = run;           // exclusive over blocks
            run += v;
        }
    }
}

// p3: both bucket-scans in one launch; blockIdx selects set.
__global__ void p3_bucketscan2(const uint* __restrict__ btotA, uint* __restrict__ bbaseA,
                               uint* __restrict__ startsA, int nbuckA, int NA,
                               const uint* __restrict__ btotB, uint* __restrict__ bbaseB,
                               uint* __restrict__ startsB, int nbuckB, int NB) {
    const uint* btot; uint* bbase; uint* starts; int nbuck; int N;
    if (blockIdx.x == 0) { btot = btotA; bbase = bbaseA; starts = startsA; nbuck = nbuckA; N = NA; }
    else                 { btot = btotB; bbase = bbaseB; starts = startsB; nbuck = nbuckB; N = NB; }
    const int t = threadIdx.x;
    __shared__ uint part[256];
    uint loc[10]; uint s = 0;
#pragma unroll
    for (int u = 0; u < 10; ++u) {
        int i = t * 10 + u;
        loc[u] = (i < nbuck) ? btot[i] : 0;
        s += loc[u];
    }
    part[t] = s;
    __syncthreads();
    for (int off = 1; off < 256; off <<= 1) {
        uint y = (t >= off) ? part[t - off] : 0;
        __syncthreads();
        part[t] += y;
        __syncthreads();
    }
    uint run = part[t] - s;
#pragma unroll
    for (int u = 0; u < 10; ++u) {
        int i = t * 10 + u;
        if (i < nbuck) { bbase[i] = run; run += loc[u]; }
    }
    if (t == 255) { bbase[nbuck] = run; starts[N] = run; }
}

// phase 4 merged: counting-sort by bucket in LDS; [0,CBLK)=A, [CBLK,2CBLK)=B.
__global__ __launch_bounds__(256)
void p4_place2(const int* __restrict__ pinA, const int* __restrict__ poutA,
               const uint* __restrict__ cntmatA, const uint* __restrict__ bbaseA,
               uint* __restrict__ tmpA, int KPA, int PA, int chunkA, int nbuckA,
               const int* __restrict__ pinB, const int* __restrict__ poutB,
               const uint* __restrict__ cntmatB, const uint* __restrict__ bbaseB,
               uint* __restrict__ tmpB, int KPB, int PB, int chunkB, int nbuckB) {
    __shared__ uint recs[LDSCAP];
    __shared__ ushort bof[LDSCAP];
    __shared__ uint H[NBUCK_MAX + 1];
    __shared__ uint C[NBUCK_MAX];
    __shared__ uint part[256];
    const int t = threadIdx.x;
    const bool isA = (blockIdx.x < CBLK);
    const int j = isA ? blockIdx.x : (blockIdx.x - CBLK);
    const int* pin = isA ? pinA : pinB;
    const int* pout = isA ? poutA : poutB;
    const uint* cntmat = isA ? cntmatA : cntmatB;
    const uint* bbase = isA ? bbaseA : bbaseB;
    uint* tmp = isA ? tmpA : tmpB;
    const int KP = isA ? KPA : KPB;
    const int P = isA ? PA : PB;
    const int chunk = isA ? chunkA : chunkB;
    const int nbuck = isA ? nbuckA : nbuckB;
    for (int i = t; i < nbuck; i += 256) H[i] = 0;
    __syncthreads();
    const int r0 = j * chunk;
    const int r1 = min(KP, r0 + chunk);
    for (int r = r0 + t; r < r1; r += 256)
        if (pin[r] >= 0) atomicAdd(&H[((uint)pout[r]) >> BKT_SH], 1u);
    __syncthreads();
    uint loc[10]; uint s = 0;
#pragma unroll
    for (int u = 0; u < 10; ++u) {
        int i = t * 10 + u;
        loc[u] = (i < nbuck) ? H[i] : 0;
        s += loc[u];
    }
    __syncthreads();
    part[t] = s;
    __syncthreads();
    for (int off = 1; off < 256; off <<= 1) {
        uint y = (t >= off) ? part[t - off] : 0;
        __syncthreads();
        part[t] += y;
        __syncthreads();
    }
    uint run = part[t] - s;
#pragma unroll
    for (int u = 0; u < 10; ++u) {
        int i = t * 10 + u;
        if (i < nbuck) { uint c = loc[u]; H[i] = run; run += c; }
    }
    if (t == 255) H[nbuck] = run;
    __syncthreads();
    for (int i = t; i < nbuck; i += 256) C[i] = H[i];   // cursors
    __syncthreads();
    for (int r = r0 + t; r < r1; r += 256) {
        int ii = pin[r];
        if (ii < 0) continue;
        uint po = (uint)pout[r];
        uint b = po >> BKT_SH;
        uint k = (uint)r / (uint)P;
        uint pos = atomicAdd(&C[b], 1u);
        recs[pos] = ((po & 255u) << 24) | (k << 19) | (uint)ii;
        bof[pos] = (ushort)b;
    }
    __syncthreads();
    const uint tot = H[nbuck];
    for (int i = t; i < nbuck; i += 256)
        C[i] = bbase[i] + cntmat[(size_t)j * nbuck + i] - H[i];  // dest bias
    __syncthreads();
    for (uint sdx = t; sdx < tot; sdx += 256) {
        uint b = (uint)bof[sdx];
        tmp[C[b] + sdx] = recs[sdx];
    }
}

// phase 5 merged: per-bucket counting-sort by local output -> starts+entries.
// entries MAY ALIAS tmp (whole range staged into LDS before any write).
__global__ void p5_fine2(const uint* tmpA, const uint* __restrict__ bbaseA,
                         uint* entriesA, uint* __restrict__ startsA, int NA, int nbuckA,
                         const uint* tmpB, const uint* __restrict__ bbaseB,
                         uint* entriesB, uint* __restrict__ startsB, int NB) {
    __shared__ uint recs[P3CAP];
    __shared__ uint cnt[256];
    __shared__ uint curl[256];
    const bool isA = ((int)blockIdx.x < nbuckA);
    const int b = isA ? blockIdx.x : (blockIdx.x - nbuckA);
    const uint* tmp = isA ? tmpA : tmpB;
    const uint* bbase = isA ? bbaseA : bbaseB;
    uint* entries = isA ? entriesA : entriesB;
    uint* starts = isA ? startsA : startsB;
    const int N = isA ? NA : NB;
    const int t = threadIdx.x;
    const uint e0 = bbase[b];
    uint nrec = bbase[b + 1] - e0;
    if (nrec > P3CAP) nrec = P3CAP;
    for (uint s = t; s < nrec; s += 256) recs[s] = tmp[e0 + s];
    cnt[t] = 0; curl[t] = 0;
    __syncthreads();
    for (uint s = t; s < nrec; s += 256) atomicAdd(&cnt[recs[s] >> 24], 1u);
    __syncthreads();
    uint orig = cnt[t];
    for (int off = 1; off < 256; off <<= 1) {
        uint y = (t >= off) ? cnt[t - off] : 0;
        __syncthreads();
        cnt[t] += y;
        __syncthreads();
    }
    cnt[t] -= orig;   // exclusive prefix per local output
    __syncthreads();
    const int o0 = b << BKT_SH;
    if (o0 + t < N) starts[o0 + t] = e0 + cnt[t];
    for (uint s = t; s < nrec; s += 256) {
        uint lo = recs[s] >> 24;
        uint idx = atomicAdd(&curl[lo], 1u);
        entries[e0 + cnt[lo] + idx] = recs[s] & 0x00FFFFFFu;
    }
}

// ------- CSR-gather MFMA conv (round-16 body), conv1 variant --------------
__global__ void conv1_csr(const ushort* __restrict__ xb,
                          const ushort* __restrict__ Wt,
                          const uint* __restrict__ starts,
                          const uint* __restrict__ entries,
                          ushort* __restrict__ outb,
                          int N) {
    const int w  = threadIdx.x >> 6;
    const int l  = threadIdx.x & 63;
    const int m  = l & 15;
    const int iq = l >> 4;
    const int o0 = (blockIdx.x * 4 + w) * 16;

    __shared__ uint eld[4][384];
    if (o0 >= N) return;

    const uint s0 = starts[o0];
    const uint sm = starts[o0 + m];
    const uint se = starts[o0 + m + 1];
    uint total = starts[o0 + 16] - s0;
    if (total > 384) total = 384;
    for (uint t = l; t < total; t += 64)
        eld[w][t] = entries[s0 + t];
    asm volatile("s_waitcnt lgkmcnt(0) vmcnt(0)" ::: "memory");
    __builtin_amdgcn_sched_barrier(0);

    if (iq == 0) {
        const uint a = sm - s0, bnd = se - s0;
        for (uint i = a + 1; i < bnd; ++i) {
            uint key = eld[w][i];
            uint j = i;
            while (j > a && eld[w][j - 1] > key) { eld[w][j] = eld[w][j - 1]; --j; }
            eld[w][j] = key;
        }
    }
    asm volatile("s_waitcnt lgkmcnt(0)" ::: "memory");
    __builtin_amdgcn_sched_barrier(0);

    f32x4 c0 = {0.f, 0.f, 0.f, 0.f};
    f32x4 c1 = {0.f, 0.f, 0.f, 0.f};
    uint q = sm - s0;
    const uint e = se - s0;
    uint ent = (q < e) ? eld[w][q] : 0xFFFFFFFFu;

    for (int k = 0; k < 27; ++k) {
        const ushort* wk = Wt + (k << 10);
        U4S8 b0, b1;
        b0.u = *(const uint4*)(wk + m * 32 + iq * 8);
        b1.u = *(const uint4*)(wk + (m + 16) * 32 + iq * 8);
        float a0=0.f,a1=0.f,a2=0.f,a3=0.f,a4=0.f,a5=0.f,a6=0.f,a7=0.f;
        bool got = false;
        while ((ent >> 19) == (uint)k) {
            got = true;
            const uint pi = ent & 0x7FFFFu;
            uint4 v = *(const uint4*)(xb + (size_t)pi * 32 + iq * 8);
            a0 += __uint_as_float(v.x << 16);
            a1 += __uint_as_float(v.x & 0xFFFF0000u);
            a2 += __uint_as_float(v.y << 16);
            a3 += __uint_as_float(v.y & 0xFFFF0000u);
            a4 += __uint_as_float(v.z << 16);
            a5 += __uint_as_float(v.z & 0xFFFF0000u);
            a6 += __uint_as_float(v.w << 16);
            a7 += __uint_as_float(v.w & 0xFFFF0000u);
            ++q;
            ent = (q < e) ? eld[w][q] : 0xFFFFFFFFu;
        }
        if (__any(got)) {
            U4S8 af;
            asm volatile("v_cvt_pk_bf16_f32 %0, %1, %2" : "=v"(af.u.x) : "v"(a0), "v"(a1));
            asm volatile("v_cvt_pk_bf16_f32 %0, %1, %2" : "=v"(af.u.y) : "v"(a2), "v"(a3));
            asm volatile("v_cvt_pk_bf16_f32 %0, %1, %2" : "=v"(af.u.z) : "v"(a4), "v"(a5));
            asm volatile("v_cvt_pk_bf16_f32 %0, %1, %2" : "=v"(af.u.w) : "v"(a6), "v"(a7));
            c0 = __builtin_amdgcn_mfma_f32_16x16x32_bf16(af.s, b0.s, c0, 0, 0, 0);
            c1 = __builtin_amdgcn_mfma_f32_16x16x32_bf16(af.s, b1.s, c1, 0, 0, 0);
        }
    }

#pragma unroll
    for (int j = 0; j < 4; ++j) {
        const long ro = (long)(o0 + iq * 4 + j) * 32;
        outb[ro + m]      = f2bf(c0[j]);
        outb[ro + 16 + m] = f2bf(c1[j]);
    }
}

// ------- conv2 (FINAL, +identity) fused with ds_gather extra blocks -------
__global__ void conv2_fused(const ushort* __restrict__ xb,
                            const ushort* __restrict__ Wt,
                            const uint* __restrict__ starts,
                            const uint* __restrict__ entries,
                            const float* __restrict__ iden,
                            float* __restrict__ outf,
                            int N, int cblocks,
                            const floatv4* __restrict__ xyzb,
                            const uint* __restrict__ starts2,
                            const uint* __restrict__ entries2,
                            float* __restrict__ out_xyz,
                            float* __restrict__ out_batch, int M) {
    if ((int)blockIdx.x >= cblocks) {
        // ---- ds_gather body ----
        int o = (blockIdx.x - cblocks) * 256 + threadIdx.x;
        if (o >= M) return;
        const uint s = starts2[o], e = starts2[o + 1];
        float sx = 0.f, sy = 0.f, sz = 0.f, sb = 0.f;
        for (uint q = s; q < e; ++q) {
            uint i = entries2[q] & 0x00FFFFFFu;
            floatv4 v = xyzb[i];
            sx += v[0]; sy += v[1]; sz += v[2]; sb += v[3];
        }
        float c = fmaxf((float)(e - s), 1.0f);
        float inv = 1.0f / c;
        out_xyz[(long)o * 3 + 0] = sx * inv;
        out_xyz[(long)o * 3 + 1] = sy * inv;
        out_xyz[(long)o * 3 + 2] = sz * inv;
        out_batch[o] = sb * inv;
        return;
    }
    const int w  = threadIdx.x >> 6;
    const int l  = threadIdx.x & 63;
    const int m  = l & 15;
    const int iq = l >> 4;
    const int o0 = (blockIdx.x * 4 + w) * 16;

    __shared__ uint eld[4][384];
    if (o0 >= N) return;

    const uint s0 = starts[o0];
    const uint sm = starts[o0 + m];
    const uint se = starts[o0 + m + 1];
    uint total = starts[o0 + 16] - s0;
    if (total > 384) total = 384;
    for (uint t = l; t < total; t += 64)
        eld[w][t] = entries[s0 + t];
    asm volatile("s_waitcnt lgkmcnt(0) vmcnt(0)" ::: "memory");
    __builtin_amdgcn_sched_barrier(0);

    if (iq == 0) {
        const uint a = sm - s0, bnd = se - s0;
        for (uint i = a + 1; i < bnd; ++i) {
            uint key = eld[w][i];
            uint j = i;
            while (j > a && eld[w][j - 1] > key) { eld[w][j] = eld[w][j - 1]; --j; }
            eld[w][j] = key;
        }
    }
    asm volatile("s_waitcnt lgkmcnt(0)" ::: "memory");
    __builtin_amdgcn_sched_barrier(0);

    f32x4 c0 = {0.f, 0.f, 0.f, 0.f};
    f32x4 c1 = {0.f, 0.f, 0.f, 0.f};
    uint q = sm - s0;
    const uint e = se - s0;
    uint ent = (q < e) ? eld[w][q] : 0xFFFFFFFFu;

    for (int k = 0; k < 27; ++k) {
        const ushort* wk = Wt + (k << 10);
        U4S8 b0, b1;
        b0.u = *(const uint4*)(wk + m * 32 + iq * 8);
        b1.u = *(const uint4*)(wk + (m + 16) * 32 + iq * 8);
        float a0=0.f,a1=0.f,a2=0.f,a3=0.f,a4=0.f,a5=0.f,a6=0.f,a7=0.f;
        bool got = false;
        while ((ent >> 19) == (uint)k) {
            got = true;
            const uint pi = ent & 0x7FFFFu;
            uint4 v = *(const uint4*)(xb + (size_t)pi * 32 + iq * 8);
            a0 += __uint_as_float(v.x << 16);
            a1 += __uint_as_float(v.x & 0xFFFF0000u);
            a2 += __uint_as_float(v.y << 16);
            a3 += __uint_as_float(v.y & 0xFFFF0000u);
            a4 += __uint_as_float(v.z << 16);
            a5 += __uint_as_float(v.z & 0xFFFF0000u);
            a6 += __uint_as_float(v.w << 16);
            a7 += __uint_as_float(v.w & 0xFFFF0000u);
            ++q;
            ent = (q < e) ? eld[w][q] : 0xFFFFFFFFu;
        }
        if (__any(got)) {
            U4S8 af;
            asm volatile("v_cvt_pk_bf16_f32 %0, %1, %2" : "=v"(af.u.x) : "v"(a0), "v"(a1));
            asm volatile("v_cvt_pk_bf16_f32 %0, %1, %2" : "=v"(af.u.y) : "v"(a2), "v"(a3));
            asm volatile("v_cvt_pk_bf16_f32 %0, %1, %2" : "=v"(af.u.z) : "v"(a4), "v"(a5));
            asm volatile("v_cvt_pk_bf16_f32 %0, %1, %2" : "=v"(af.u.w) : "v"(a6), "v"(a7));
            c0 = __builtin_amdgcn_mfma_f32_16x16x32_bf16(af.s, b0.s, c0, 0, 0, 0);
            c1 = __builtin_amdgcn_mfma_f32_16x16x32_bf16(af.s, b1.s, c1, 0, 0, 0);
        }
    }

#pragma unroll
    for (int j = 0; j < 4; ++j) {
        const long ro = (long)(o0 + iq * 4 + j) * 32;
        outf[ro + m]      = c0[j] + iden[ro + m];
        outf[ro + 16 + m] = c1[j] + iden[ro + 16 + m];
    }
}

extern "C" void kernel_launch(void* const* d_in, const int* in_sizes, int n_in,
                              void* d_out, int out_size, void* d_ws, size_t ws_size,
                              hipStream_t stream) {
    const float* feats = (const float*)d_in[0];
    const float* xyz   = (const float*)d_in[1];
    const int*   batch = (const int*)d_in[2];
    const int*   pin   = (const int*)d_in[3];
    const int*   pout  = (const int*)d_in[4];
    const int*   dsin  = (const int*)d_in[5];
    const int*   dsout = (const int*)d_in[6];
    const float* W1    = (const float*)d_in[7];
    const float* W2    = (const float*)d_in[8];

    const int N   = in_sizes[0] / 32;
    const int K   = 27;
    const int P   = in_sizes[3] / K;
    const int KP  = K * P;
    const int P2n = in_sizes[5];
    const int M   = (out_size - N * 32) / 4;
    const int nbuck = (N + 255) >> BKT_SH;       // 1172 for N=300000
    const int chunk = (KP + CBLK - 1) / CBLK;    // 3956 <= LDSCAP
    const int nbuck2 = (M + 255) >> BKT_SH;      // 147
    const int chunk2 = (P2n + CBLK - 1) / CBLK;  // 293

    auto align256 = [](size_t x) { return (x + 255) & ~(size_t)255; };
    char* base = (char*)d_ws;
    size_t off = 0;
    float* stats1 = (float*)(base + off); off += 256;
    float* stats2 = (float*)(base + off); off += 256;
    const size_t zero_end = off;
    uint* cntmat  = (uint*)(base + off);  off = align256(off + (size_t)CBLK * nbuck * 4);
    uint* btot    = (uint*)(base + off);  off = align256(off + (size_t)nbuck * 4);
    uint* bbase   = (uint*)(base + off);  off = align256(off + (size_t)(nbuck + 1) * 4);
    uint* starts  = (uint*)(base + off);  off = align256(off + (size_t)(N + 1) * 4);
    uint* tmp     = (uint*)(base + off);  off = align256(off + (size_t)KP * 4);
    uint* entries = tmp;                  // built in place by p5
    uint* cntmat2 = (uint*)(base + off);  off = align256(off + (size_t)CBLK * nbuck2 * 4);
    uint* btot2   = (uint*)(base + off);  off = align256(off + (size_t)nbuck2 * 4);
    uint* bbase2  = (uint*)(base + off);  off = align256(off + (size_t)(nbuck2 + 1) * 4);
    uint* starts2 = (uint*)(base + off);  off = align256(off + (size_t)(M + 1) * 4);
    uint* tmp2    = (uint*)(base + off);  off = align256(off + (size_t)P2n * 4);
    uint* entries2 = tmp2;                // built in place by p5
    ushort* Wt1   = (ushort*)(base + off); off = align256(off + 27 * 1024 * 2);
    ushort* Wt2   = (ushort*)(base + off); off = align256(off + 27 * 1024 * 2);
    ushort* xb    = (ushort*)(base + off); off = align256(off + (size_t)(N + 1) * 64);
    ushort* hacc  = (ushort*)(base + off); off = align256(off + (size_t)N * 64);
    floatv4* xyzb = (floatv4*)(base + off); off = align256(off + (size_t)N * 16);

    hipMemsetAsync(d_ws, 0, zero_end, stream);

    // prep (W transpose, zero-row, xyzb pack) + stats1 over feats, one launch
    const int B0 = (2 * 27 * 1024 + 32 + N + 255) / 256;
    prep2<<<B0 + 1024, 256, 0, stream>>>(W1, W2, Wt1, Wt2, xb, xyz, batch, xyzb,
                                         N, B0, feats, stats1, N * 8);

    // CSR builds (conv set A + ds set B), merged launches
    p1_count2<<<2 * CBLK, 256, 0, stream>>>(pin, pout, cntmat, KP, chunk, nbuck,
                                            dsin, dsout, cntmat2, P2n, chunk2, nbuck2);
    const int nblkA = (nbuck + 15) / 16, nblkB = (nbuck2 + 15) / 16;
    p2_colscan2<<<nblkA + nblkB, 256, 0, stream>>>(cntmat, btot, nbuck, nblkA,
                                                   cntmat2, btot2, nbuck2);
    p3_bucketscan2<<<2, 256, 0, stream>>>(btot, bbase, starts, nbuck, N,
                                          btot2, bbase2, starts2, nbuck2, M);
    p4_place2<<<2 * CBLK, 256, 0, stream>>>(pin, pout, cntmat, bbase, tmp, KP, P, chunk, nbuck,
                                            dsin, dsout, cntmat2, bbase2, tmp2, P2n, P2n, chunk2, nbuck2);
    p5_fine2<<<nbuck + nbuck2, 256, 0, stream>>>(tmp, bbase, entries, starts, N, nbuck,
                                                 tmp2, bbase2, entries2, starts2, M);

    // conv1: bn_relu(feats) -> W1 -> hacc (bf16)
    bnrelu_f32<<<(N * 4 + 255) / 256, 256, 0, stream>>>(feats, stats1, xb, N * 4, N);
    const int cblocks = (N / 16 + 3) / 4;
    conv1_csr<<<cblocks, 256, 0, stream>>>(xb, Wt1, starts, entries, hacc, N);

    // conv2: bn_relu(hacc) -> W2 -> out (+ identity), fused with ds_gather
    stats_bf16<<<1024, 256, 0, stream>>>(hacc, stats2, N * 4);
    bnrelu_bf16<<<(N * 4 + 255) / 256, 256, 0, stream>>>(hacc, stats2, xb, N * 4, N);
    float* out = (float*)d_out;
    const int dsblocks = (M + 255) / 256;
    conv2_fused<<<cblocks + dsblocks, 256, 0, stream>>>(
        xb, Wt2, starts, entries, feats, out, N, cblocks,
        xyzb, starts2, entries2,
        out + (size_t)N * 32, out + (size_t)N * 32 + (size_t)3 * M, M);
}

// Round 18
// 432.447 us; speedup vs baseline: 1.1672x; 1.0025x over previous
//
#include <hip/hip_runtime.h>

#define BN_EPS 1e-4f
#define BKT_SH 8          // 256 outputs per bucket (local-out fits 8 bits)
#define NBUCK_MAX 2560
#define CBLK 1024         // blocks in count/place phases (4 blocks/CU)
#define LDSCAP 4096       // max records per place-block (chunk = 3956)
#define P3CAP 4096        // max records per bucket (avg ~3.1K)

typedef __attribute__((ext_vector_type(8))) short short8;   // 8 bf16
typedef __attribute__((ext_vector_type(4))) float f32x4;    // MFMA acc
typedef __attribute__((ext_vector_type(4))) float floatv4;
typedef unsigned int uint;

union U4S8 { uint4 u; short8 s; };

// float -> bf16 bits, round-to-nearest-even
static __device__ __forceinline__ unsigned short f2bf(float f) {
    unsigned u = __float_as_uint(f);
    unsigned r = (u + 0x7FFFu + ((u >> 16) & 1u)) >> 16;
    return (unsigned short)r;
}

// ---------------- BN stats over bf16 [N,32] ----------------
__global__ void stats_bf16(const ushort* __restrict__ x,
                           float* __restrict__ stats, int n8) {
    const int t = threadIdx.x;
    long idx = (long)blockIdx.x * 256 + t;
    const long stride = (long)gridDim.x * 256;
    float s[8] = {0}, q[8] = {0};
    const uint4* x8 = (const uint4*)x;
    for (long e = idx; e < n8; e += stride) {
        uint4 v = x8[e];
        uint w0 = v.x, w1 = v.y, w2 = v.z, w3 = v.w;
        float f0 = __uint_as_float(w0 << 16), f1 = __uint_as_float(w0 & 0xFFFF0000u);
        float f2 = __uint_as_float(w1 << 16), f3 = __uint_as_float(w1 & 0xFFFF0000u);
        float f4 = __uint_as_float(w2 << 16), f5 = __uint_as_float(w2 & 0xFFFF0000u);
        float f6 = __uint_as_float(w3 << 16), f7 = __uint_as_float(w3 & 0xFFFF0000u);
        s[0]+=f0; q[0]+=f0*f0; s[1]+=f1; q[1]+=f1*f1;
        s[2]+=f2; q[2]+=f2*f2; s[3]+=f3; q[3]+=f3*f3;
        s[4]+=f4; q[4]+=f4*f4; s[5]+=f5; q[5]+=f5*f5;
        s[6]+=f6; q[6]+=f6*f6; s[7]+=f7; q[7]+=f7*f7;
    }
    __shared__ float red[256][8];
#pragma unroll
    for (int j = 0; j < 8; ++j) red[t][j] = s[j];
    __syncthreads();
    if (t < 32) {
        float a = 0.f;
        const int grp = t >> 3, j = t & 7;
#pragma unroll
        for (int m = 0; m < 64; ++m) a += red[grp + 4 * m][j];
        atomicAdd(&stats[t], a);
    }
    __syncthreads();
#pragma unroll
    for (int j = 0; j < 8; ++j) red[t][j] = q[j];
    __syncthreads();
    if (t < 32) {
        float a = 0.f;
        const int grp = t >> 3, j = t & 7;
#pragma unroll
        for (int m = 0; m < 64; ++m) a += red[grp + 4 * m][j];
        atomicAdd(&stats[32 + t], a);
    }
}

// ---------------- bn_relu + cast to bf16 (bf16 input) ----------------
__global__ void bnrelu_bf16(const ushort* __restrict__ h,
                            const float* __restrict__ stats,
                            ushort* __restrict__ xb, int n8, int N) {
    int idx = blockIdx.x * 256 + threadIdx.x;
    if (idx >= n8) return;
    const int c0 = (idx & 3) * 8;
    const float invN = 1.0f / (float)N;
    uint4 v = *(const uint4*)(h + (size_t)idx * 8);
    uint w[4] = {v.x, v.y, v.z, v.w};
    uint r[8];
#pragma unroll
    for (int j = 0; j < 8; ++j) {
        const int c = c0 + j;
        float mu = stats[c] * invN;
        float var = stats[32 + c] * invN - mu * mu;
        float rs = rsqrtf(var + BN_EPS);
        uint bits = (j & 1) ? (w[j >> 1] & 0xFFFF0000u) : (w[j >> 1] << 16);
        float f = __uint_as_float(bits);
        float xn = fmaxf((f - mu) * rs, 0.f);
        r[j] = (uint)f2bf(xn);
    }
    uint4 o;
    o.x = r[0] | (r[1] << 16); o.y = r[2] | (r[3] << 16);
    o.z = r[4] | (r[5] << 16); o.w = r[6] | (r[7] << 16);
    *(uint4*)(xb + (size_t)idx * 8) = o;
}

// --- prep2: prep work (blocks < B0) + stats_f32 over feats (1024 blocks) --
__global__ void prep2(const float* __restrict__ W1, const float* __restrict__ W2,
                      ushort* __restrict__ Wt1, ushort* __restrict__ Wt2,
                      ushort* __restrict__ xb,
                      const float* __restrict__ xyz, const int* __restrict__ batch,
                      floatv4* __restrict__ xyzb, int N, int B0,
                      const float* __restrict__ feats, float* __restrict__ stats1,
                      int total4) {
    const int t = threadIdx.x;
    if ((int)blockIdx.x >= B0) {
        const int bid = blockIdx.x - B0;
        long idx = (long)bid * 256 + t;
        const long stride = 1024L * 256;
        float s[4] = {0.f, 0.f, 0.f, 0.f}, q[4] = {0.f, 0.f, 0.f, 0.f};
        const floatv4* x4 = (const floatv4*)feats;
        for (long e = idx; e < total4; e += stride) {
            floatv4 v = x4[e];
#pragma unroll
            for (int j = 0; j < 4; ++j) { s[j] += v[j]; q[j] += v[j] * v[j]; }
        }
        __shared__ float red[256][4];
#pragma unroll
        for (int j = 0; j < 4; ++j) red[t][j] = s[j];
        __syncthreads();
        if (t < 32) {
            float a = 0.f;
            const int grp = t >> 2, j = t & 3;
#pragma unroll
            for (int m = 0; m < 32; ++m) a += red[grp + 8 * m][j];
            atomicAdd(&stats1[t], a);
        }
        __syncthreads();
#pragma unroll
        for (int j = 0; j < 4; ++j) red[t][j] = q[j];
        __syncthreads();
        if (t < 32) {
            float a = 0.f;
            const int grp = t >> 2, j = t & 3;
#pragma unroll
            for (int m = 0; m < 32; ++m) a += red[grp + 8 * m][j];
            atomicAdd(&stats1[32 + t], a);
        }
        return;
    }
    int idx = blockIdx.x * 256 + t;
    if (idx < 27 * 1024) {
        int k = idx >> 10, r = idx & 1023, co = r >> 5, ci = r & 31;
        Wt1[(k << 10) + (co << 5) + ci] = f2bf(W1[(k << 10) + (ci << 5) + co]);
    } else if (idx < 2 * 27 * 1024) {
        int i2 = idx - 27 * 1024;
        int k = i2 >> 10, r = i2 & 1023, co = r >> 5, ci = r & 31;
        Wt2[(k << 10) + (co << 5) + ci] = f2bf(W2[(k << 10) + (ci << 5) + co]);
    } else if (idx < 2 * 27 * 1024 + 32) {
        xb[(size_t)N * 32 + (idx - 2 * 27 * 1024)] = 0;
    } else {
        int i = idx - (2 * 27 * 1024 + 32);
        if (i < N) {
            floatv4 v;
            v[0] = xyz[(size_t)i * 3 + 0];
            v[1] = xyz[(size_t)i * 3 + 1];
            v[2] = xyz[(size_t)i * 3 + 2];
            v[3] = (float)batch[i];
            xyzb[i] = v;
        }
    }
}

// ============ CSR build: atomic-free MSD bucket sort (shape-generic) ======
// bucket = pout >> 8 (256 outputs). Record = (po&255)<<24 | k<<19 | pin.

// p1 merged + bnrelu_f32 rider: [0,CBLK)=A count, [CBLK,2CBLK)=B count,
// [2CBLK, 2CBLK+bnblk) = bn_relu(feats)->xb (depends only on stats1/feats).
__global__ void p1_count2(const int* __restrict__ pinA, const int* __restrict__ poutA,
                          uint* __restrict__ cntmatA, int KPA, int chunkA, int nbuckA,
                          const int* __restrict__ pinB, const int* __restrict__ poutB,
                          uint* __restrict__ cntmatB, int KPB, int chunkB, int nbuckB,
                          const float* __restrict__ feats, const float* __restrict__ stats1,
                          ushort* __restrict__ xb, int n8, int N) {
    const int t = threadIdx.x;
    if ((int)blockIdx.x >= 2 * CBLK) {
        // ---- bnrelu_f32 body ----
        int idx = ((int)blockIdx.x - 2 * CBLK) * 256 + t;
        if (idx >= n8) return;
        const int c0 = (idx & 3) * 8;
        const float invN = 1.0f / (float)N;
        floatv4 v0 = *(const floatv4*)(feats + (size_t)idx * 8);
        floatv4 v1 = *(const floatv4*)(feats + (size_t)idx * 8 + 4);
        uint r[8];
#pragma unroll
        for (int j = 0; j < 8; ++j) {
            const int c = c0 + j;
            float mu = stats1[c] * invN;
            float var = stats1[32 + c] * invN - mu * mu;
            float rs = rsqrtf(var + BN_EPS);
            float f = (j < 4) ? v0[j] : v1[j - 4];
            float xn = fmaxf((f - mu) * rs, 0.f);
            r[j] = (uint)f2bf(xn);
        }
        uint4 o;
        o.x = r[0] | (r[1] << 16); o.y = r[2] | (r[3] << 16);
        o.z = r[4] | (r[5] << 16); o.w = r[6] | (r[7] << 16);
        *(uint4*)(xb + (size_t)idx * 8) = o;
        return;
    }
    __shared__ uint H[NBUCK_MAX];
    const bool isA = (blockIdx.x < CBLK);
    const int j = isA ? blockIdx.x : (blockIdx.x - CBLK);
    const int* pin = isA ? pinA : pinB;
    const int* pout = isA ? poutA : poutB;
    uint* cntmat = isA ? cntmatA : cntmatB;
    const int KP = isA ? KPA : KPB;
    const int chunk = isA ? chunkA : chunkB;
    const int nbuck = isA ? nbuckA : nbuckB;
    for (int i = t; i < nbuck; i += 256) H[i] = 0;
    __syncthreads();
    const int r0 = j * chunk;
    const int r1 = min(KP, r0 + chunk);
    for (int r = r0 + t; r < r1; r += 256)
        if (pin[r] >= 0) atomicAdd(&H[((uint)pout[r]) >> BKT_SH], 1u);
    __syncthreads();
    uint* row = cntmat + (size_t)j * nbuck;
    for (int i = t; i < nbuck; i += 256) row[i] = H[i];
}

// p2 merged: blocks [0,nblkA) scan set A; rest set B.
__global__ void p2_colscan2(uint* __restrict__ cntmatA, uint* __restrict__ btotA,
                            int nbuckA, int nblkA,
                            uint* __restrict__ cntmatB, uint* __restrict__ btotB,
                            int nbuckB) {
    const bool isA = ((int)blockIdx.x < nblkA);
    const int blk = isA ? blockIdx.x : (blockIdx.x - nblkA);
    uint* cntmat = isA ? cntmatA : cntmatB;
    uint* btot = isA ? btotA : btotB;
    const int nbuck = isA ? nbuckA : nbuckB;
    const int tid = threadIdx.x;
    const int bi  = tid & 15;
    const int seg = tid >> 4;            // 0..15
    const int b   = blk * 16 + bi;
    const int rpseg = CBLK / 16;         // 64 rows per segment
    const bool valid = (b < nbuck);
    uint s = 0;
    if (valid) {
        for (int u = 0; u < rpseg; ++u)
            s += cntmat[(size_t)(seg * rpseg + u) * nbuck + b];
    }
    __shared__ uint ss[16][16];
    ss[seg][bi] = s;
    __syncthreads();
    uint pre = 0;
    for (int g = 0; g < seg; ++g) pre += ss[g][bi];
    if (valid && seg == 15) btot[b] = pre + s;
    if (valid) {
        uint run = pre;
        for (int u = 0; u < rpseg; ++u) {
            size_t idx = (size_t)(seg * rpseg + u) * nbuck + b;
            uint v = cntmat[idx];
            cntmat[idx] = run;           // exclusive over blocks
            run += v;
        }
    }
}

// p3: both bucket-scans in one launch; blockIdx selects set.
__global__ void p3_bucketscan2(const uint* __restrict__ btotA, uint* __restrict__ bbaseA,
                               uint* __restrict__ startsA, int nbuckA, int NA,
                               const uint* __restrict__ btotB, uint* __restrict__ bbaseB,
                               uint* __restrict__ startsB, int nbuckB, int NB) {
    const uint* btot; uint* bbase; uint* starts; int nbuck; int N;
    if (blockIdx.x == 0) { btot = btotA; bbase = bbaseA; starts = startsA; nbuck = nbuckA; N = NA; }
    else                 { btot = btotB; bbase = bbaseB; starts = startsB; nbuck = nbuckB; N = NB; }
    const int t = threadIdx.x;
    __shared__ uint part[256];
    uint loc[10]; uint s = 0;
#pragma unroll
    for (int u = 0; u < 10; ++u) {
        int i = t * 10 + u;
        loc[u] = (i < nbuck) ? btot[i] : 0;
        s += loc[u];
    }
    part[t] = s;
    __syncthreads();
    for (int off = 1; off < 256; off <<= 1) {
        uint y = (t >= off) ? part[t - off] : 0;
        __syncthreads();
        part[t] += y;
        __syncthreads();
    }
    uint run = part[t] - s;
#pragma unroll
    for (int u = 0; u < 10; ++u) {
        int i = t * 10 + u;
        if (i < nbuck) { bbase[i] = run; run += loc[u]; }
    }
    if (t == 255) { bbase[nbuck] = run; starts[N] = run; }
}

// phase 4 merged: counting-sort by bucket in LDS; [0,CBLK)=A, [CBLK,2CBLK)=B.
__global__ __launch_bounds__(256)
void p4_place2(const int* __restrict__ pinA, const int* __restrict__ poutA,
               const uint* __restrict__ cntmatA, const uint* __restrict__ bbaseA,
               uint* __restrict__ tmpA, int KPA, int PA, int chunkA, int nbuckA,
               const int* __restrict__ pinB, const int* __restrict__ poutB,
               const uint* __restrict__ cntmatB, const uint* __restrict__ bbaseB,
               uint* __restrict__ tmpB, int KPB, int PB, int chunkB, int nbuckB) {
    __shared__ uint recs[LDSCAP];
    __shared__ ushort bof[LDSCAP];
    __shared__ uint H[NBUCK_MAX + 1];
    __shared__ uint C[NBUCK_MAX];
    __shared__ uint part[256];
    const int t = threadIdx.x;
    const bool isA = (blockIdx.x < CBLK);
    const int j = isA ? blockIdx.x : (blockIdx.x - CBLK);
    const int* pin = isA ? pinA : pinB;
    const int* pout = isA ? poutA : poutB;
    const uint* cntmat = isA ? cntmatA : cntmatB;
    const uint* bbase = isA ? bbaseA : bbaseB;
    uint* tmp = isA ? tmpA : tmpB;
    const int KP = isA ? KPA : KPB;
    const int P = isA ? PA : PB;
    const int chunk = isA ? chunkA : chunkB;
    const int nbuck = isA ? nbuckA : nbuckB;
    for (int i = t; i < nbuck; i += 256) H[i] = 0;
    __syncthreads();
    const int r0 = j * chunk;
    const int r1 = min(KP, r0 + chunk);
    for (int r = r0 + t; r < r1; r += 256)
        if (pin[r] >= 0) atomicAdd(&H[((uint)pout[r]) >> BKT_SH], 1u);
    __syncthreads();
    uint loc[10]; uint s = 0;
#pragma unroll
    for (int u = 0; u < 10; ++u) {
        int i = t * 10 + u;
        loc[u] = (i < nbuck) ? H[i] : 0;
        s += loc[u];
    }
    __syncthreads();
    part[t] = s;
    __syncthreads();
    for (int off = 1; off < 256; off <<= 1) {
        uint y = (t >= off) ? part[t - off] : 0;
        __syncthreads();
        part[t] += y;
        __syncthreads();
    }
    uint run = part[t] - s;
#pragma unroll
    for (int u = 0; u < 10; ++u) {
        int i = t * 10 + u;
        if (i < nbuck) { uint c = loc[u]; H[i] = run; run += c; }
    }
    if (t == 255) H[nbuck] = run;
    __syncthreads();
    for (int i = t; i < nbuck; i += 256) C[i] = H[i];   // cursors
    __syncthreads();
    for (int r = r0 + t; r < r1; r += 256) {
        int ii = pin[r];
        if (ii < 0) continue;
        uint po = (uint)pout[r];
        uint b = po >> BKT_SH;
        uint k = (uint)r / (uint)P;
        uint pos = atomicAdd(&C[b], 1u);
        recs[pos] = ((po & 255u) << 24) | (k << 19) | (uint)ii;
        bof[pos] = (ushort)b;
    }
    __syncthreads();
    const uint tot = H[nbuck];
    for (int i = t; i < nbuck; i += 256)
        C[i] = bbase[i] + cntmat[(size_t)j * nbuck + i] - H[i];  // dest bias
    __syncthreads();
    for (uint sdx = t; sdx < tot; sdx += 256) {
        uint b = (uint)bof[sdx];
        tmp[C[b] + sdx] = recs[sdx];
    }
}

// phase 5 merged: per-bucket counting-sort by local output, then per-output
// value sort (thread t owns local output t) -> starts + SORTED entries.
// Conv keeps its own sort as determinism guard (linear scan on sorted data).
// entries MAY ALIAS tmp (whole range staged into LDS before any write).
__global__ void p5_fine2(const uint* tmpA, const uint* __restrict__ bbaseA,
                         uint* entriesA, uint* __restrict__ startsA, int NA, int nbuckA,
                         const uint* tmpB, const uint* __restrict__ bbaseB,
                         uint* entriesB, uint* __restrict__ startsB, int NB) {
    __shared__ uint recs[P3CAP];
    __shared__ uint locs[P3CAP];
    __shared__ uint cnt[256];
    __shared__ uint curl[256];
    const bool isA = ((int)blockIdx.x < nbuckA);
    const int b = isA ? blockIdx.x : (blockIdx.x - nbuckA);
    const uint* tmp = isA ? tmpA : tmpB;
    const uint* bbase = isA ? bbaseA : bbaseB;
    uint* entries = isA ? entriesA : entriesB;
    uint* starts = isA ? startsA : startsB;
    const int N = isA ? NA : NB;
    const int t = threadIdx.x;
    const uint e0 = bbase[b];
    uint nrec = bbase[b + 1] - e0;
    if (nrec > P3CAP) nrec = P3CAP;
    for (uint s = t; s < nrec; s += 256) recs[s] = tmp[e0 + s];
    cnt[t] = 0; curl[t] = 0;
    __syncthreads();
    for (uint s = t; s < nrec; s += 256) atomicAdd(&cnt[recs[s] >> 24], 1u);
    __syncthreads();
    uint orig = cnt[t];
    for (int off = 1; off < 256; off <<= 1) {
        uint y = (t >= off) ? cnt[t - off] : 0;
        __syncthreads();
        cnt[t] += y;
        __syncthreads();
    }
    cnt[t] -= orig;   // exclusive prefix per local output
    __syncthreads();
    const int o0 = b << BKT_SH;
    if (o0 + t < N) starts[o0 + t] = e0 + cnt[t];
    for (uint s = t; s < nrec; s += 256) {
        uint lo = recs[s] >> 24;
        uint idx = atomicAdd(&curl[lo], 1u);
        locs[cnt[lo] + idx] = recs[s];
    }
    __syncthreads();
    // thread t sorts local output t's segment by raw u32 (top byte uniform)
    {
        const uint a = cnt[t], bnd = a + curl[t];
        for (uint i = a + 1; i < bnd; ++i) {
            uint key = locs[i];
            uint j2 = i;
            while (j2 > a && locs[j2 - 1] > key) { locs[j2] = locs[j2 - 1]; --j2; }
            locs[j2] = key;
        }
    }
    __syncthreads();
    for (uint s = t; s < nrec; s += 256) entries[e0 + s] = locs[s] & 0x00FFFFFFu;
}

// ------- CSR-gather MFMA conv (round-17 body), conv1 variant --------------
__global__ void conv1_csr(const ushort* __restrict__ xb,
                          const ushort* __restrict__ Wt,
                          const uint* __restrict__ starts,
                          const uint* __restrict__ entries,
                          ushort* __restrict__ outb,
                          int N) {
    const int w  = threadIdx.x >> 6;
    const int l  = threadIdx.x & 63;
    const int m  = l & 15;
    const int iq = l >> 4;
    const int o0 = (blockIdx.x * 4 + w) * 16;

    __shared__ uint eld[4][384];
    if (o0 >= N) return;

    const uint s0 = starts[o0];
    const uint sm = starts[o0 + m];
    const uint se = starts[o0 + m + 1];
    uint total = starts[o0 + 16] - s0;
    if (total > 384) total = 384;
    for (uint t = l; t < total; t += 64)
        eld[w][t] = entries[s0 + t];
    asm volatile("s_waitcnt lgkmcnt(0) vmcnt(0)" ::: "memory");
    __builtin_amdgcn_sched_barrier(0);

    // determinism guard: linear scan if p5 already sorted (it does)
    if (iq == 0) {
        const uint a = sm - s0, bnd = se - s0;
        for (uint i = a + 1; i < bnd; ++i) {
            uint key = eld[w][i];
            uint j = i;
            while (j > a && eld[w][j - 1] > key) { eld[w][j] = eld[w][j - 1]; --j; }
            eld[w][j] = key;
        }
    }
    asm volatile("s_waitcnt lgkmcnt(0)" ::: "memory");
    __builtin_amdgcn_sched_barrier(0);

    f32x4 c0 = {0.f, 0.f, 0.f, 0.f};
    f32x4 c1 = {0.f, 0.f, 0.f, 0.f};
    uint q = sm - s0;
    const uint e = se - s0;
    uint ent = (q < e) ? eld[w][q] : 0xFFFFFFFFu;

    for (int k = 0; k < 27; ++k) {
        const ushort* wk = Wt + (k << 10);
        U4S8 b0, b1;
        b0.u = *(const uint4*)(wk + m * 32 + iq * 8);
        b1.u = *(const uint4*)(wk + (m + 16) * 32 + iq * 8);
        float a0=0.f,a1=0.f,a2=0.f,a3=0.f,a4=0.f,a5=0.f,a6=0.f,a7=0.f;
        bool got = false;
        while ((ent >> 19) == (uint)k) {
            got = true;
            const uint pi = ent & 0x7FFFFu;
            uint4 v = *(const uint4*)(xb + (size_t)pi * 32 + iq * 8);
            a0 += __uint_as_float(v.x << 16);
            a1 += __uint_as_float(v.x & 0xFFFF0000u);
            a2 += __uint_as_float(v.y << 16);
            a3 += __uint_as_float(v.y & 0xFFFF0000u);
            a4 += __uint_as_float(v.z << 16);
            a5 += __uint_as_float(v.z & 0xFFFF0000u);
            a6 += __uint_as_float(v.w << 16);
            a7 += __uint_as_float(v.w & 0xFFFF0000u);
            ++q;
            ent = (q < e) ? eld[w][q] : 0xFFFFFFFFu;
        }
        if (__any(got)) {
            U4S8 af;
            asm volatile("v_cvt_pk_bf16_f32 %0, %1, %2" : "=v"(af.u.x) : "v"(a0), "v"(a1));
            asm volatile("v_cvt_pk_bf16_f32 %0, %1, %2" : "=v"(af.u.y) : "v"(a2), "v"(a3));
            asm volatile("v_cvt_pk_bf16_f32 %0, %1, %2" : "=v"(af.u.z) : "v"(a4), "v"(a5));
            asm volatile("v_cvt_pk_bf16_f32 %0, %1, %2" : "=v"(af.u.w) : "v"(a6), "v"(a7));
            c0 = __builtin_amdgcn_mfma_f32_16x16x32_bf16(af.s, b0.s, c0, 0, 0, 0);
            c1 = __builtin_amdgcn_mfma_f32_16x16x32_bf16(af.s, b1.s, c1, 0, 0, 0);
        }
    }

#pragma unroll
    for (int j = 0; j < 4; ++j) {
        const long ro = (long)(o0 + iq * 4 + j) * 32;
        outb[ro + m]      = f2bf(c0[j]);
        outb[ro + 16 + m] = f2bf(c1[j]);
    }
}

// ------- conv2 (FINAL, +identity) fused with ds_gather extra blocks -------
__global__ void conv2_fused(const ushort* __restrict__ xb,
                            const ushort* __restrict__ Wt,
                            const uint* __restrict__ starts,
                            const uint* __restrict__ entries,
                            const float* __restrict__ iden,
                            float* __restrict__ outf,
                            int N, int cblocks,
                            const floatv4* __restrict__ xyzb,
                            const uint* __restrict__ starts2,
                            const uint* __restrict__ entries2,
                            float* __restrict__ out_xyz,
                            float* __restrict__ out_batch, int M) {
    if ((int)blockIdx.x >= cblocks) {
        int o = (blockIdx.x - cblocks) * 256 + threadIdx.x;
        if (o >= M) return;
        const uint s = starts2[o], e = starts2[o + 1];
        float sx = 0.f, sy = 0.f, sz = 0.f, sb = 0.f;
        for (uint q = s; q < e; ++q) {
            uint i = entries2[q] & 0x00FFFFFFu;
            floatv4 v = xyzb[i];
            sx += v[0]; sy += v[1]; sz += v[2]; sb += v[3];
        }
        float c = fmaxf((float)(e - s), 1.0f);
        float inv = 1.0f / c;
        out_xyz[(long)o * 3 + 0] = sx * inv;
        out_xyz[(long)o * 3 + 1] = sy * inv;
        out_xyz[(long)o * 3 + 2] = sz * inv;
        out_batch[o] = sb * inv;
        return;
    }
    const int w  = threadIdx.x >> 6;
    const int l  = threadIdx.x & 63;
    const int m  = l & 15;
    const int iq = l >> 4;
    const int o0 = (blockIdx.x * 4 + w) * 16;

    __shared__ uint eld[4][384];
    if (o0 >= N) return;

    const uint s0 = starts[o0];
    const uint sm = starts[o0 + m];
    const uint se = starts[o0 + m + 1];
    uint total = starts[o0 + 16] - s0;
    if (total > 384) total = 384;
    for (uint t = l; t < total; t += 64)
        eld[w][t] = entries[s0 + t];
    asm volatile("s_waitcnt lgkmcnt(0) vmcnt(0)" ::: "memory");
    __builtin_amdgcn_sched_barrier(0);

    if (iq == 0) {
        const uint a = sm - s0, bnd = se - s0;
        for (uint i = a + 1; i < bnd; ++i) {
            uint key = eld[w][i];
            uint j = i;
            while (j > a && eld[w][j - 1] > key) { eld[w][j] = eld[w][j - 1]; --j; }
            eld[w][j] = key;
        }
    }
    asm volatile("s_waitcnt lgkmcnt(0)" ::: "memory");
    __builtin_amdgcn_sched_barrier(0);

    f32x4 c0 = {0.f, 0.f, 0.f, 0.f};
    f32x4 c1 = {0.f, 0.f, 0.f, 0.f};
    uint q = sm - s0;
    const uint e = se - s0;
    uint ent = (q < e) ? eld[w][q] : 0xFFFFFFFFu;

    for (int k = 0; k < 27; ++k) {
        const ushort* wk = Wt + (k << 10);
        U4S8 b0, b1;
        b0.u = *(const uint4*)(wk + m * 32 + iq * 8);
        b1.u = *(const uint4*)(wk + (m + 16) * 32 + iq * 8);
        float a0=0.f,a1=0.f,a2=0.f,a3=0.f,a4=0.f,a5=0.f,a6=0.f,a7=0.f;
        bool got = false;
        while ((ent >> 19) == (uint)k) {
            got = true;
            const uint pi = ent & 0x7FFFFu;
            uint4 v = *(const uint4*)(xb + (size_t)pi * 32 + iq * 8);
            a0 += __uint_as_float(v.x << 16);
            a1 += __uint_as_float(v.x & 0xFFFF0000u);
            a2 += __uint_as_float(v.y << 16);
            a3 += __uint_as_float(v.y & 0xFFFF0000u);
            a4 += __uint_as_float(v.z << 16);
            a5 += __uint_as_float(v.z & 0xFFFF0000u);
            a6 += __uint_as_float(v.w << 16);
            a7 += __uint_as_float(v.w & 0xFFFF0000u);
            ++q;
            ent = (q < e) ? eld[w][q] : 0xFFFFFFFFu;
        }
        if (__any(got)) {
            U4S8 af;
            asm volatile("v_cvt_pk_bf16_f32 %0, %1, %2" : "=v"(af.u.x) : "v"(a0), "v"(a1));
            asm volatile("v_cvt_pk_bf16_f32 %0, %1, %2" : "=v"(af.u.y) : "v"(a2), "v"(a3));
            asm volatile("v_cvt_pk_bf16_f32 %0, %1, %2" : "=v"(af.u.z) : "v"(a4), "v"(a5));
            asm volatile("v_cvt_pk_bf16_f32 %0, %1, %2" : "=v"(af.u.w) : "v"(a6), "v"(a7));
            c0 = __builtin_amdgcn_mfma_f32_16x16x32_bf16(af.s, b0.s, c0, 0, 0, 0);
            c1 = __builtin_amdgcn_mfma_f32_16x16x32_bf16(af.s, b1.s, c1, 0, 0, 0);
        }
    }

#pragma unroll
    for (int j = 0; j < 4; ++j) {
        const long ro = (long)(o0 + iq * 4 + j) * 32;
        outf[ro + m]      = c0[j] + iden[ro + m];
        outf[ro + 16 + m] = c1[j] + iden[ro + 16 + m];
    }
}

extern "C" void kernel_launch(void* const* d_in, const int* in_sizes, int n_in,
                              void* d_out, int out_size, void* d_ws, size_t ws_size,
                              hipStream_t stream) {
    const float* feats = (const float*)d_in[0];
    const float* xyz   = (const float*)d_in[1];
    const int*   batch = (const int*)d_in[2];
    const int*   pin   = (const int*)d_in[3];
    const int*   pout  = (const int*)d_in[4];
    const int*   dsin  = (const int*)d_in[5];
    const int*   dsout = (const int*)d_in[6];
    const float* W1    = (const float*)d_in[7];
    const float* W2    = (const float*)d_in[8];

    const int N   = in_sizes[0] / 32;
    const int K   = 27;
    const int P   = in_sizes[3] / K;
    const int KP  = K * P;
    const int P2n = in_sizes[5];
    const int M   = (out_size - N * 32) / 4;
    const int nbuck = (N + 255) >> BKT_SH;       // 1172 for N=300000
    const int chunk = (KP + CBLK - 1) / CBLK;    // 3956 <= LDSCAP
    const int nbuck2 = (M + 255) >> BKT_SH;      // 147
    const int chunk2 = (P2n + CBLK - 1) / CBLK;  // 293

    auto align256 = [](size_t x) { return (x + 255) & ~(size_t)255; };
    char* base = (char*)d_ws;
    size_t off = 0;
    float* stats1 = (float*)(base + off); off += 256;
    float* stats2 = (float*)(base + off); off += 256;
    const size_t zero_end = off;
    uint* cntmat  = (uint*)(base + off);  off = align256(off + (size_t)CBLK * nbuck * 4);
    uint* btot    = (uint*)(base + off);  off = align256(off + (size_t)nbuck * 4);
    uint* bbase   = (uint*)(base + off);  off = align256(off + (size_t)(nbuck + 1) * 4);
    uint* starts  = (uint*)(base + off);  off = align256(off + (size_t)(N + 1) * 4);
    uint* tmp     = (uint*)(base + off);  off = align256(off + (size_t)KP * 4);
    uint* entries = tmp;                  // built in place by p5
    uint* cntmat2 = (uint*)(base + off);  off = align256(off + (size_t)CBLK * nbuck2 * 4);
    uint* btot2   = (uint*)(base + off);  off = align256(off + (size_t)nbuck2 * 4);
    uint* bbase2  = (uint*)(base + off);  off = align256(off + (size_t)(nbuck2 + 1) * 4);
    uint* starts2 = (uint*)(base + off);  off = align256(off + (size_t)(M + 1) * 4);
    uint* tmp2    = (uint*)(base + off);  off = align256(off + (size_t)P2n * 4);
    uint* entries2 = tmp2;                // built in place by p5
    ushort* Wt1   = (ushort*)(base + off); off = align256(off + 27 * 1024 * 2);
    ushort* Wt2   = (ushort*)(base + off); off = align256(off + 27 * 1024 * 2);
    ushort* xb    = (ushort*)(base + off); off = align256(off + (size_t)(N + 1) * 64);
    ushort* hacc  = (ushort*)(base + off); off = align256(off + (size_t)N * 64);
    floatv4* xyzb = (floatv4*)(base + off); off = align256(off + (size_t)N * 16);

    hipMemsetAsync(d_ws, 0, zero_end, stream);

    // prep (W transpose, zero-row, xyzb pack) + stats1 over feats, one launch
    const int B0 = (2 * 27 * 1024 + 32 + N + 255) / 256;
    prep2<<<B0 + 1024, 256, 0, stream>>>(W1, W2, Wt1, Wt2, xb, xyz, batch, xyzb,
                                         N, B0, feats, stats1, N * 8);

    // CSR builds (conv A + ds B) + bnrelu_f32 rider
    const int bnblk = (N * 4 + 255) / 256;
    p1_count2<<<2 * CBLK + bnblk, 256, 0, stream>>>(
        pin, pout, cntmat, KP, chunk, nbuck,
        dsin, dsout, cntmat2, P2n, chunk2, nbuck2,
        feats, stats1, xb, N * 4, N);
    const int nblkA = (nbuck + 15) / 16, nblkB = (nbuck2 + 15) / 16;
    p2_colscan2<<<nblkA + nblkB, 256, 0, stream>>>(cntmat, btot, nbuck, nblkA,
                                                   cntmat2, btot2, nbuck2);
    p3_bucketscan2<<<2, 256, 0, stream>>>(btot, bbase, starts, nbuck, N,
                                          btot2, bbase2, starts2, nbuck2, M);
    p4_place2<<<2 * CBLK, 256, 0, stream>>>(pin, pout, cntmat, bbase, tmp, KP, P, chunk, nbuck,
                                            dsin, dsout, cntmat2, bbase2, tmp2, P2n, P2n, chunk2, nbuck2);
    p5_fine2<<<nbuck + nbuck2, 256, 0, stream>>>(tmp, bbase, entries, starts, N, nbuck,
                                                 tmp2, bbase2, entries2, starts2, M);

    // conv1: bn_relu(feats) -> W1 -> hacc (bf16)
    const int cblocks = (N / 16 + 3) / 4;
    conv1_csr<<<cblocks, 256, 0, stream>>>(xb, Wt1, starts, entries, hacc, N);

    // conv2: bn_relu(hacc) -> W2 -> out (+ identity), fused with ds_gather
    stats_bf16<<<1024, 256, 0, stream>>>(hacc, stats2, N * 4);
    bnrelu_bf16<<<(N * 4 + 255) / 256, 256, 0, stream>>>(hacc, stats2, xb, N * 4, N);
    float* out = (float*)d_out;
    const int dsblocks = (M + 255) / 256;
    conv2_fused<<<cblocks + dsblocks, 256, 0, stream>>>(
        xb, Wt2, starts, entries, feats, out, N, cblocks,
        xyzb, starts2, entries2,
        out + (size_t)N * 32, out + (size_t)N * 32 + (size_t)3 * M, M);
}